// Round 1
// baseline (10697.192 us; speedup 1.0000x reference)
//
#include <hip/hip_runtime.h>
#include <hip/hip_bf16.h>

using u16 = unsigned short;
using u32 = unsigned int;
using bf16x8 = __attribute__((ext_vector_type(8))) __bf16;
using f32x4  = __attribute__((ext_vector_type(4))) float;

#define GLP(p) ((const __attribute__((address_space(1))) void*)(p))
#define LDSP(p) ((__attribute__((address_space(3))) void*)(p))

__device__ __forceinline__ float bf2f(u16 u) {
    union { float f; u32 i; } v; v.i = ((u32)u) << 16; return v.f;
}
__device__ __forceinline__ u16 f2bf(float f) {
    union { float f; u32 i; } v; v.f = f;
    u32 r = v.i + 0x7FFFu + ((v.i >> 16) & 1u);
    return (u16)(r >> 16);
}

// ---------------- gather: X0[t*32+n][k] = bf16(emb[x[n][t]][k]) ----------------
__global__ void k_gather(const int* __restrict__ x, const float* __restrict__ emb,
                         u16* __restrict__ X0) {
    int gid = blockIdx.x * blockDim.x + threadIdx.x;   // one thread per 4 elems
    if (gid >= 16384 * 256) return;
    int e4 = gid << 2;
    int m = e4 >> 10, k = e4 & 1023;
    int t = m >> 5, n = m & 31;
    int tok = x[n * 512 + t];
    float4 v = *reinterpret_cast<const float4*>(emb + ((size_t)tok << 10) + k);
    ushort4 o;
    o.x = f2bf(v.x); o.y = f2bf(v.y); o.z = f2bf(v.z); o.w = f2bf(v.w);
    *reinterpret_cast<ushort4*>(X0 + (size_t)e4) = o;
}

// ---------------- fp32 -> bf16 bulk convert ----------------
__global__ void k_f32bf16(const float* __restrict__ s, u16* __restrict__ d, int n4) {
    int gid = blockIdx.x * blockDim.x + threadIdx.x;
    if (gid >= n4) return;
    float4 v = reinterpret_cast<const float4*>(s)[gid];
    ushort4 o;
    o.x = f2bf(v.x); o.y = f2bf(v.y); o.z = f2bf(v.z); o.w = f2bf(v.w);
    reinterpret_cast<ushort4*>(d)[gid] = o;
}

// ---------------- GEMM: C[M][N] = A[M][K] * B[N][K]^T + bias[N], bf16 in/out ----
// 128x128 tile, BK=64, 4 waves (2x2), 16x16x32 MFMA, global_load_lds w=16,
// XOR-swizzled LDS (byte ^= (row&7)<<4) to kill ds_read_b128 bank conflicts.
__global__ __launch_bounds__(256) void k_gemm(const u16* __restrict__ A,
                                              const u16* __restrict__ B,
                                              const float* __restrict__ bias,
                                              u16* __restrict__ C,
                                              int M, int N, int K) {
    __shared__ __align__(16) u16 As[128 * 64];
    __shared__ __align__(16) u16 Bs[128 * 64];
    const int tid = threadIdx.x;
    const int lane = tid & 63, wid = tid >> 6;
    const int wm = wid >> 1, wn = wid & 1;
    const int m0 = blockIdx.y * 128, n0 = blockIdx.x * 128;
    const int lr = lane & 15, lk = lane >> 4;
    f32x4 zero = {0.f, 0.f, 0.f, 0.f};
    f32x4 acc[4][4];
    #pragma unroll
    for (int i = 0; i < 4; ++i)
        #pragma unroll
        for (int j = 0; j < 4; ++j) acc[i][j] = zero;

    for (int k0 = 0; k0 < K; k0 += 64) {
        // stage 16 KB A + 16 KB B (16 chunks of 1KB each); source pre-swizzled
        #pragma unroll
        for (int r = 0; r < 4; ++r) {
            int c = wid * 4 + r;               // 0..15
            int o = c * 1024 + lane * 16;      // linear byte offset in tile
            int row = o >> 7;                  // 0..127
            int kb = o & 127;
            int kbs = kb ^ ((row & 7) << 4);
            const char* sa = (const char*)A + ((size_t)(m0 + row) * K + k0) * 2 + kbs;
            const char* sb = (const char*)B + ((size_t)(n0 + row) * K + k0) * 2 + kbs;
            __builtin_amdgcn_global_load_lds(GLP(sa), LDSP((char*)As + c * 1024), 16, 0, 0);
            __builtin_amdgcn_global_load_lds(GLP(sb), LDSP((char*)Bs + c * 1024), 16, 0, 0);
        }
        __syncthreads();
        #pragma unroll
        for (int kk = 0; kk < 2; ++kk) {
            bf16x8 af[4], bfr[4];
            #pragma unroll
            for (int i = 0; i < 4; ++i) {
                int rowA = wm * 64 + i * 16 + lr;
                int rowB = wn * 64 + i * 16 + lr;
                int kb = kk * 64 + lk * 16;
                af[i]  = *reinterpret_cast<const bf16x8*>((const char*)As + rowA * 128 + (kb ^ ((rowA & 7) << 4)));
                bfr[i] = *reinterpret_cast<const bf16x8*>((const char*)Bs + rowB * 128 + (kb ^ ((rowB & 7) << 4)));
            }
            #pragma unroll
            for (int i = 0; i < 4; ++i)
                #pragma unroll
                for (int j = 0; j < 4; ++j)
                    acc[i][j] = __builtin_amdgcn_mfma_f32_16x16x32_bf16(af[i], bfr[j], acc[i][j], 0, 0, 0);
        }
        __syncthreads();
    }
    // epilogue: add bias, store bf16
    #pragma unroll
    for (int j = 0; j < 4; ++j) {
        int col = n0 + wn * 64 + j * 16 + lr;
        float bv = bias[col];
        #pragma unroll
        for (int i = 0; i < 4; ++i) {
            int rowb = m0 + wm * 64 + i * 16 + lk * 4;
            #pragma unroll
            for (int q = 0; q < 4; ++q)
                C[(size_t)(rowb + q) * N + col] = f2bf(acc[i][j][q] + bv);
        }
    }
}

// ---------------- GRU layer scan ----------------
// grid = 32 WGs: blockIdx>>4 = dir, &15 = j-slice (32 h-outputs each).
// 384 threads = 6 waves; wave w owns gate rows {group g = w>>1} x {16 j's, joff=(w&1)*16}.
// W_hh fragments live in VGPRs for all 512 steps. h broadcast via global hbuf
// (bf16, double-buffered) with a per-dir monotonic atomic counter barrier.
__global__ __launch_bounds__(384) void k_gru(const u16* __restrict__ Gi,   // [16384][3072]
                                             const u16* __restrict__ Whh,  // [3072][512] (this layer)
                                             const float* __restrict__ bhh,// [3072]  (this layer)
                                             u16* __restrict__ hbuf,       // [2][2][32][512]
                                             u16* __restrict__ X1,         // layer0 out, [16384][1024]
                                             float* __restrict__ hid,      // hiddens base
                                             float* __restrict__ outp,     // outputs base
                                             int layer,
                                             u32* __restrict__ ctr) {      // [2]
    __shared__ float ghs[32][101];
    __shared__ u16   gis[32][104];
    __shared__ float bhh_s[96];
    const int tid = threadIdx.x;
    const int lane = tid & 63, w = tid >> 6;
    const int d = blockIdx.x >> 4, wg = blockIdx.x & 15;
    const int j0 = wg * 32;
    const int g = w >> 1, joff = (w & 1) * 16;
    const int lr = lane & 15, lk = lane >> 4;

    if (tid < 96) {
        int g2 = tid >> 5, jj = tid & 31;
        bhh_s[tid] = bhh[d * 1536 + g2 * 512 + j0 + jj];
    }
    // pin W_hh fragments (16 k-tiles x 4 VGPRs) in registers
    bf16x8 wf[16];
    {
        const u16* wr = Whh + (size_t)(d * 1536 + g * 512 + j0 + joff + lr) * 512 + lk * 8;
        #pragma unroll
        for (int kt = 0; kt < 16; ++kt)
            wf[kt] = *reinterpret_cast<const bf16x8*>(wr + kt * 32);
    }
    __syncthreads();

    // gi prefetch mapping: thread -> (batch p_nb, 8-gate chunk p_gc)
    const int p_nb = tid / 12, p_gc = tid % 12;
    const int p_lg = p_gc * 8;
    const int p_col = d * 1536 + (p_lg >> 5) * 512 + j0 + (p_lg & 31);

    float hp0 = 0.f, hp1 = 0.f, hp2 = 0.f;

    for (int t = 0; t < 512; ++t) {
        // issue gi load early (overlaps barrier spin)
        uint4 gv = *reinterpret_cast<const uint4*>(Gi + (size_t)(t * 32 + p_nb) * 3072 + p_col);

        if (t > 0) {
            if (tid == 0) {
                u32 target = 16u * (u32)t;
                while (__hip_atomic_load(&ctr[d], __ATOMIC_RELAXED, __HIP_MEMORY_SCOPE_AGENT) < target)
                    __builtin_amdgcn_s_sleep(1);
            }
            __syncthreads();
            __builtin_amdgcn_fence(__ATOMIC_ACQUIRE, "agent");  // invalidate L1/L2 -> fresh h
        }

        // gh = h(t-1) @ Whh^T for this wave's 16 gate rows, both batch halves
        const u16* hb = hbuf + ((size_t)d * 2 + ((t + 1) & 1)) * 16384;
        f32x4 acc0 = {0.f, 0.f, 0.f, 0.f}, acc1 = acc0;
        const u16* hr0 = hb + (size_t)lr * 512 + lk * 8;
        const u16* hr1 = hb + (size_t)(16 + lr) * 512 + lk * 8;
        #pragma unroll
        for (int kt = 0; kt < 16; ++kt) {
            bf16x8 a0 = *reinterpret_cast<const bf16x8*>(hr0 + kt * 32);
            bf16x8 a1 = *reinterpret_cast<const bf16x8*>(hr1 + kt * 32);
            acc0 = __builtin_amdgcn_mfma_f32_16x16x32_bf16(a0, wf[kt], acc0, 0, 0, 0);
            acc1 = __builtin_amdgcn_mfma_f32_16x16x32_bf16(a1, wf[kt], acc1, 0, 0, 0);
        }
        // gh + b_hh -> LDS (C layout: col=lane&15 -> gate, row=(lane>>4)*4+q -> batch)
        int colg = w * 16 + lr;
        float bv = bhh_s[colg];
        #pragma unroll
        for (int q = 0; q < 4; ++q) {
            ghs[lk * 4 + q][colg]      = acc0[q] + bv;
            ghs[16 + lk * 4 + q][colg] = acc1[q] + bv;
        }
        *reinterpret_cast<uint4*>(&gis[p_nb][p_lg]) = gv;
        __syncthreads();

        // gates + h' ; e -> j = e&31 (fast, coalesced stores), nb = e>>5
        u16* hbw = hbuf + ((size_t)d * 2 + (t & 1)) * 16384;
        #pragma unroll
        for (int rep = 0; rep < 3; ++rep) {
            int e = tid + rep * 384;
            if (e < 1024) {
                int j = e & 31, nb = e >> 5;
                float gr = bf2f(gis[nb][j])      + ghs[nb][j];
                float gz = bf2f(gis[nb][32 + j]) + ghs[nb][32 + j];
                float r = 1.f / (1.f + __expf(-gr));
                float z = 1.f / (1.f + __expf(-gz));
                float ng = tanhf(bf2f(gis[nb][64 + j]) + r * ghs[nb][64 + j]);
                float hp = (rep == 0) ? hp0 : (rep == 1) ? hp1 : hp2;
                float hv = (1.f - z) * ng + z * hp;
                if (rep == 0) hp0 = hv; else if (rep == 1) hp1 = hv; else hp2 = hv;
                // device-visible bf16 h for next step's matvec (bypasses caches)
                __hip_atomic_store(hbw + (size_t)nb * 512 + j0 + j, f2bf(hv),
                                   __ATOMIC_RELAXED, __HIP_MEMORY_SCOPE_AGENT);
                hid[((size_t)(t * 4 + layer * 2 + d) * 32 + nb) * 512 + j0 + j] = hv;
                if (layer == 0)
                    X1[((size_t)(t * 32 + nb)) * 1024 + (size_t)d * 512 + j0 + j] = f2bf(hv);
                else
                    outp[((size_t)nb * 512 + t) * 1024 + (size_t)d * 512 + j0 + j] = hv;
            }
        }
        __syncthreads();   // drains all stores (vmcnt(0) before s_barrier)
        if (tid == 0)
            __hip_atomic_fetch_add(&ctr[d], 1u, __ATOMIC_RELEASE, __HIP_MEMORY_SCOPE_AGENT);
    }
}

extern "C" void kernel_launch(void* const* d_in, const int* in_sizes, int n_in,
                              void* d_out, int out_size, void* d_ws, size_t ws_size,
                              hipStream_t stream) {
    const int*   x    = (const int*)d_in[0];
    const float* emb  = (const float*)d_in[1];
    const float* w_ih = (const float*)d_in[2];
    const float* w_hh = (const float*)d_in[3];
    const float* b_ih = (const float*)d_in[4];
    const float* b_hh = (const float*)d_in[5];
    float* outp = (float*)d_out;
    float* hid  = outp + (size_t)32 * 512 * 1024;   // outputs | hiddens

    char* ws = (char*)d_ws;
    u16* X0   = (u16*)(ws);                          //  33,554,432 B
    u16* X1   = (u16*)(ws + 33554432);               //  33,554,432 B
    u16* Wih  = (u16*)(ws + 67108864);               //  12,582,912 B  [2][3072][1024]
    u16* Whh  = (u16*)(ws + 79691776);               //   6,291,456 B  [2][3072][512]
    u16* Gi   = (u16*)(ws + 85983232);               // 100,663,296 B  [16384][3072]
    u16* hbuf = (u16*)(ws + 186646528);              //     131,072 B  [2][2][32][512]
    u32* ctr  = (u32*)(ws + 186777600);              //         256 B

    k_gather<<<16384, 256, 0, stream>>>(x, emb, X0);
    k_f32bf16<<<(1572864 + 255) / 256, 256, 0, stream>>>(w_ih, Wih, 1572864);
    k_f32bf16<<<( 786432 + 255) / 256, 256, 0, stream>>>(w_hh, Whh, 786432);

    // ---- layer 0 ----
    hipMemsetAsync(hbuf, 0, 131072 + 256, stream);
    k_gemm<<<dim3(24, 128), 256, 0, stream>>>(X0, Wih, b_ih, Gi, 16384, 3072, 1024);
    k_gru<<<32, 384, 0, stream>>>(Gi, Whh, b_hh, hbuf, X1, hid, outp, 0, ctr);

    // ---- layer 1 ----
    hipMemsetAsync(hbuf, 0, 131072 + 256, stream);
    k_gemm<<<dim3(24, 128), 256, 0, stream>>>(X1, Wih + (size_t)3072 * 1024, b_ih + 3072,
                                              Gi, 16384, 3072, 1024);
    k_gru<<<32, 384, 0, stream>>>(Gi, Whh + (size_t)3072 * 512, b_hh + 3072, hbuf,
                                  nullptr, hid, outp, 1, ctr);
}

// Round 2
// 9303.507 us; speedup vs baseline: 1.1498x; 1.1498x over previous
//
#include <hip/hip_runtime.h>
#include <hip/hip_bf16.h>

using u16 = unsigned short;
using u32 = unsigned int;
using bf16x8 = __attribute__((ext_vector_type(8))) __bf16;
using f32x4  = __attribute__((ext_vector_type(4))) float;

#define GLP(p) ((const __attribute__((address_space(1))) void*)(p))
#define LDSP(p) ((__attribute__((address_space(3))) void*)(p))

__device__ __forceinline__ float bf2f(u16 u) {
    union { float f; u32 i; } v; v.i = ((u32)u) << 16; return v.f;
}
__device__ __forceinline__ u16 f2bf(float f) {
    union { float f; u32 i; } v; v.f = f;
    u32 r = v.i + 0x7FFFu + ((v.i >> 16) & 1u);
    return (u16)(r >> 16);
}

// ---------------- gather: X0[t*32+n][k] = bf16(emb[x[n][t]][k]) ----------------
__global__ void k_gather(const int* __restrict__ x, const float* __restrict__ emb,
                         u16* __restrict__ X0) {
    int gid = blockIdx.x * blockDim.x + threadIdx.x;   // one thread per 4 elems
    if (gid >= 16384 * 256) return;
    int e4 = gid << 2;
    int m = e4 >> 10, k = e4 & 1023;
    int t = m >> 5, n = m & 31;
    int tok = x[n * 512 + t];
    float4 v = *reinterpret_cast<const float4*>(emb + ((size_t)tok << 10) + k);
    ushort4 o;
    o.x = f2bf(v.x); o.y = f2bf(v.y); o.z = f2bf(v.z); o.w = f2bf(v.w);
    *reinterpret_cast<ushort4*>(X0 + (size_t)e4) = o;
}

// ---------------- fp32 -> bf16 bulk convert ----------------
__global__ void k_f32bf16(const float* __restrict__ s, u16* __restrict__ d, int n4) {
    int gid = blockIdx.x * blockDim.x + threadIdx.x;
    if (gid >= n4) return;
    float4 v = reinterpret_cast<const float4*>(s)[gid];
    ushort4 o;
    o.x = f2bf(v.x); o.y = f2bf(v.y); o.z = f2bf(v.z); o.w = f2bf(v.w);
    reinterpret_cast<ushort4*>(d)[gid] = o;
}

// ---------------- GEMM: C[M][N] = A[M][K] * B[N][K]^T + bias[N], bf16 in/out ----
__global__ __launch_bounds__(256) void k_gemm(const u16* __restrict__ A,
                                              const u16* __restrict__ B,
                                              const float* __restrict__ bias,
                                              u16* __restrict__ C,
                                              int M, int N, int K) {
    __shared__ __align__(16) u16 As[128 * 64];
    __shared__ __align__(16) u16 Bs[128 * 64];
    const int tid = threadIdx.x;
    const int lane = tid & 63, wid = tid >> 6;
    const int wm = wid >> 1, wn = wid & 1;
    const int m0 = blockIdx.y * 128, n0 = blockIdx.x * 128;
    const int lr = lane & 15, lk = lane >> 4;
    f32x4 zero = {0.f, 0.f, 0.f, 0.f};
    f32x4 acc[4][4];
    #pragma unroll
    for (int i = 0; i < 4; ++i)
        #pragma unroll
        for (int j = 0; j < 4; ++j) acc[i][j] = zero;

    for (int k0 = 0; k0 < K; k0 += 64) {
        #pragma unroll
        for (int r = 0; r < 4; ++r) {
            int c = wid * 4 + r;               // 0..15
            int o = c * 1024 + lane * 16;      // linear byte offset in tile
            int row = o >> 7;                  // 0..127
            int kb = o & 127;
            int kbs = kb ^ ((row & 7) << 4);
            const char* sa = (const char*)A + ((size_t)(m0 + row) * K + k0) * 2 + kbs;
            const char* sb = (const char*)B + ((size_t)(n0 + row) * K + k0) * 2 + kbs;
            __builtin_amdgcn_global_load_lds(GLP(sa), LDSP((char*)As + c * 1024), 16, 0, 0);
            __builtin_amdgcn_global_load_lds(GLP(sb), LDSP((char*)Bs + c * 1024), 16, 0, 0);
        }
        __syncthreads();
        #pragma unroll
        for (int kk = 0; kk < 2; ++kk) {
            bf16x8 af[4], bfr[4];
            #pragma unroll
            for (int i = 0; i < 4; ++i) {
                int rowA = wm * 64 + i * 16 + lr;
                int rowB = wn * 64 + i * 16 + lr;
                int kb = kk * 64 + lk * 16;
                af[i]  = *reinterpret_cast<const bf16x8*>((const char*)As + rowA * 128 + (kb ^ ((rowA & 7) << 4)));
                bfr[i] = *reinterpret_cast<const bf16x8*>((const char*)Bs + rowB * 128 + (kb ^ ((rowB & 7) << 4)));
            }
            #pragma unroll
            for (int i = 0; i < 4; ++i)
                #pragma unroll
                for (int j = 0; j < 4; ++j)
                    acc[i][j] = __builtin_amdgcn_mfma_f32_16x16x32_bf16(af[i], bfr[j], acc[i][j], 0, 0, 0);
        }
        __syncthreads();
    }
    #pragma unroll
    for (int j = 0; j < 4; ++j) {
        int col = n0 + wn * 64 + j * 16 + lr;
        float bv = bias[col];
        #pragma unroll
        for (int i = 0; i < 4; ++i) {
            int rowb = m0 + wm * 64 + i * 16 + lk * 4;
            #pragma unroll
            for (int q = 0; q < 4; ++q)
                C[(size_t)(rowb + q) * N + col] = f2bf(acc[i][j][q] + bv);
        }
    }
}

// ---------------- GRU layer scan ----------------
// grid = 32 WGs: blockIdx>>4 = dir, &15 = j-slice (32 h-outputs each).
// Sync: per-WG epoch flags (128B-spaced lines, release store; 16 parallel
// spinners) instead of a contended fetch_add counter. Output stores deferred
// until after the flag release so only the 2KB h-exchange is in the drain.
__global__ __launch_bounds__(384) void k_gru(const u16* __restrict__ Gi,   // [16384][3072]
                                             const u16* __restrict__ Whh,  // [3072][512] (this layer)
                                             const float* __restrict__ bhh,// [3072]  (this layer)
                                             u16* __restrict__ hbuf,       // [2][2][32][512]
                                             u16* __restrict__ X1,         // layer0 out, [16384][1024]
                                             float* __restrict__ hid,      // hiddens base
                                             float* __restrict__ outp,     // outputs base
                                             int layer,
                                             u32* __restrict__ flags) {    // [2][16][32]
    __shared__ float ghs[32][101];
    __shared__ u16   gis[32][104];
    __shared__ float bhh_s[96];
    const int tid = threadIdx.x;
    const int lane = tid & 63, w = tid >> 6;
    const int d = blockIdx.x >> 4, wg = blockIdx.x & 15;
    const int j0 = wg * 32;
    const int g = w >> 1, joff = (w & 1) * 16;
    const int lr = lane & 15, lk = lane >> 4;

    if (tid < 96) {
        int g2 = tid >> 5, jj = tid & 31;
        bhh_s[tid] = bhh[d * 1536 + g2 * 512 + j0 + jj];
    }
    // pin W_hh fragments (16 k-tiles x 4 VGPRs) in registers
    bf16x8 wf[16];
    {
        const u16* wr = Whh + (size_t)(d * 1536 + g * 512 + j0 + joff + lr) * 512 + lk * 8;
        #pragma unroll
        for (int kt = 0; kt < 16; ++kt)
            wf[kt] = *reinterpret_cast<const bf16x8*>(wr + kt * 32);
    }
    __syncthreads();

    // gi prefetch mapping: thread -> (batch p_nb, 8-gate chunk p_gc)
    const int p_nb = tid / 12, p_gc = tid % 12;
    const int p_lg = p_gc * 8;
    const int p_col = d * 1536 + (p_lg >> 5) * 512 + j0 + (p_lg & 31);

    float hp0 = 0.f, hp1 = 0.f, hp2 = 0.f;

    for (int t = 0; t < 512; ++t) {
        // issue gi load early (overlaps barrier spin)
        uint4 gv = *reinterpret_cast<const uint4*>(Gi + (size_t)(t * 32 + p_nb) * 3072 + p_col);

        if (t > 0) {
            if (tid < 16) {
                const u32* fp = flags + (d * 16 + tid) * 32;
                while (__hip_atomic_load(fp, __ATOMIC_RELAXED, __HIP_MEMORY_SCOPE_AGENT) < (u32)t)
                    __builtin_amdgcn_s_sleep(2);
            }
            __syncthreads();
            __builtin_amdgcn_fence(__ATOMIC_ACQUIRE, "agent");  // fresh h
        }

        // gh = h(t-1) @ Whh^T for this wave's 16 gate rows, both batch halves
        const u16* hb = hbuf + ((size_t)d * 2 + ((t + 1) & 1)) * 16384;
        f32x4 acc0 = {0.f, 0.f, 0.f, 0.f}, acc1 = acc0;
        const u16* hr0 = hb + (size_t)lr * 512 + lk * 8;
        const u16* hr1 = hb + (size_t)(16 + lr) * 512 + lk * 8;
        #pragma unroll
        for (int kt = 0; kt < 16; ++kt) {
            bf16x8 a0 = *reinterpret_cast<const bf16x8*>(hr0 + kt * 32);
            bf16x8 a1 = *reinterpret_cast<const bf16x8*>(hr1 + kt * 32);
            acc0 = __builtin_amdgcn_mfma_f32_16x16x32_bf16(a0, wf[kt], acc0, 0, 0, 0);
            acc1 = __builtin_amdgcn_mfma_f32_16x16x32_bf16(a1, wf[kt], acc1, 0, 0, 0);
        }
        // gh + b_hh -> LDS (C layout: col=lane&15 -> gate, row=(lane>>4)*4+q -> batch)
        int colg = w * 16 + lr;
        float bv = bhh_s[colg];
        #pragma unroll
        for (int q = 0; q < 4; ++q) {
            ghs[lk * 4 + q][colg]      = acc0[q] + bv;
            ghs[16 + lk * 4 + q][colg] = acc1[q] + bv;
        }
        *reinterpret_cast<uint4*>(&gis[p_nb][p_lg]) = gv;
        __syncthreads();

        // gates + h' ; only the h-exchange store happens before the flag
        u16* hbw = hbuf + ((size_t)d * 2 + (t & 1)) * 16384;
        #pragma unroll
        for (int rep = 0; rep < 3; ++rep) {
            int e = tid + rep * 384;
            if (e < 1024) {
                int j = e & 31, nb = e >> 5;
                float gr = bf2f(gis[nb][j])      + ghs[nb][j];
                float gz = bf2f(gis[nb][32 + j]) + ghs[nb][32 + j];
                float r = 1.f / (1.f + __expf(-gr));
                float z = 1.f / (1.f + __expf(-gz));
                float ng = tanhf(bf2f(gis[nb][64 + j]) + r * ghs[nb][64 + j]);
                float hp = (rep == 0) ? hp0 : (rep == 1) ? hp1 : hp2;
                float hv = (1.f - z) * ng + z * hp;
                if (rep == 0) hp0 = hv; else if (rep == 1) hp1 = hv; else hp2 = hv;
                __hip_atomic_store(hbw + (size_t)nb * 512 + j0 + j, f2bf(hv),
                                   __ATOMIC_RELAXED, __HIP_MEMORY_SCOPE_AGENT);
            }
        }
        __syncthreads();   // all waves' h stores drained (vmcnt(0) before s_barrier)
        if (tid == 0)
            __hip_atomic_store(flags + (d * 16 + wg) * 32, (u32)(t + 1),
                               __ATOMIC_RELEASE, __HIP_MEMORY_SCOPE_AGENT);

        // deferred output stores: drain in the background of next step's spin
        #pragma unroll
        for (int rep = 0; rep < 3; ++rep) {
            int e = tid + rep * 384;
            if (e < 1024) {
                int j = e & 31, nb = e >> 5;
                float hv = (rep == 0) ? hp0 : (rep == 1) ? hp1 : hp2;
                hid[((size_t)(t * 4 + layer * 2 + d) * 32 + nb) * 512 + j0 + j] = hv;
                if (layer == 0)
                    X1[((size_t)(t * 32 + nb)) * 1024 + (size_t)d * 512 + j0 + j] = f2bf(hv);
                else
                    outp[((size_t)nb * 512 + t) * 1024 + (size_t)d * 512 + j0 + j] = hv;
            }
        }
    }
}

extern "C" void kernel_launch(void* const* d_in, const int* in_sizes, int n_in,
                              void* d_out, int out_size, void* d_ws, size_t ws_size,
                              hipStream_t stream) {
    const int*   x    = (const int*)d_in[0];
    const float* emb  = (const float*)d_in[1];
    const float* w_ih = (const float*)d_in[2];
    const float* w_hh = (const float*)d_in[3];
    const float* b_ih = (const float*)d_in[4];
    const float* b_hh = (const float*)d_in[5];
    float* outp = (float*)d_out;
    float* hid  = outp + (size_t)32 * 512 * 1024;   // outputs | hiddens

    char* ws = (char*)d_ws;
    u16* X0    = (u16*)(ws);                          //  33,554,432 B
    u16* X1    = (u16*)(ws + 33554432);               //  33,554,432 B
    u16* Wih   = (u16*)(ws + 67108864);               //  12,582,912 B  [2][3072][1024]
    u16* Whh   = (u16*)(ws + 79691776);               //   6,291,456 B  [2][3072][512]
    u16* Gi    = (u16*)(ws + 85983232);               // 100,663,296 B  [16384][3072]
    u16* hbuf  = (u16*)(ws + 186646528);              //     131,072 B  [2][2][32][512]
    u32* flags = (u32*)(ws + 186777600);              //       4,096 B  [2][16][32]

    k_gather<<<16384, 256, 0, stream>>>(x, emb, X0);
    k_f32bf16<<<(1572864 + 255) / 256, 256, 0, stream>>>(w_ih, Wih, 1572864);
    k_f32bf16<<<( 786432 + 255) / 256, 256, 0, stream>>>(w_hh, Whh, 786432);

    // ---- layer 0 ----
    hipMemsetAsync(hbuf, 0, 131072 + 4096, stream);
    k_gemm<<<dim3(24, 128), 256, 0, stream>>>(X0, Wih, b_ih, Gi, 16384, 3072, 1024);
    k_gru<<<32, 384, 0, stream>>>(Gi, Whh, b_hh, hbuf, X1, hid, outp, 0, flags);

    // ---- layer 1 ----
    hipMemsetAsync(hbuf, 0, 131072 + 4096, stream);
    k_gemm<<<dim3(24, 128), 256, 0, stream>>>(X1, Wih + (size_t)3072 * 1024, b_ih + 3072,
                                              Gi, 16384, 3072, 1024);
    k_gru<<<32, 384, 0, stream>>>(Gi, Whh + (size_t)3072 * 512, b_hh + 3072, hbuf,
                                  nullptr, hid, outp, 1, flags);
}

// Round 4
// 8066.684 us; speedup vs baseline: 1.3261x; 1.1533x over previous
//
#include <hip/hip_runtime.h>
#include <hip/hip_bf16.h>

using u16 = unsigned short;
using u32 = unsigned int;
using bf16x8 = __attribute__((ext_vector_type(8))) __bf16;
using f32x4  = __attribute__((ext_vector_type(4))) float;

#define GLP(p) ((const __attribute__((address_space(1))) void*)(p))
#define LDSP(p) ((__attribute__((address_space(3))) void*)(p))

__device__ __forceinline__ float bf2f(u16 u) {
    union { float f; u32 i; } v; v.i = ((u32)u) << 16; return v.f;
}
__device__ __forceinline__ u16 f2bf(float f) {
    union { float f; u32 i; } v; v.f = f;
    u32 r = v.i + 0x7FFFu + ((v.i >> 16) & 1u);
    return (u16)(r >> 16);
}

// LLC-coherent primitives: bypass L1 AND L2 (coherence point = LLC/MALL).
// R2 empirically proved the load side sees remote updates (its spin worked
// cross-XCD); the store side is backstopped by a release re-publish (below).
__device__ __forceinline__ u32 ld_sc01_u32(const u32* p) {
    u32 v;
    asm volatile("global_load_dword %0, %1, off sc0 sc1\n\ts_waitcnt vmcnt(0)"
                 : "=v"(v) : "v"(p) : "memory");
    return v;
}
__device__ __forceinline__ void st_sc01_u32(u32* p, u32 v) {
    asm volatile("global_store_dword %0, %1, off sc0 sc1" :: "v"(p), "v"(v) : "memory");
}
__device__ __forceinline__ void st_sc01_u16(u16* p, u16 v) {
    asm volatile("global_store_short %0, %1, off sc0 sc1" :: "v"(p), "v"(v) : "memory");
}

// ---------------- gather: X0[t*32+n][k] = bf16(emb[x[n][t]][k]) ----------------
__global__ void k_gather(const int* __restrict__ x, const float* __restrict__ emb,
                         u16* __restrict__ X0) {
    int gid = blockIdx.x * blockDim.x + threadIdx.x;
    if (gid >= 16384 * 256) return;
    int e4 = gid << 2;
    int m = e4 >> 10, k = e4 & 1023;
    int t = m >> 5, n = m & 31;
    int tok = x[n * 512 + t];
    float4 v = *reinterpret_cast<const float4*>(emb + ((size_t)tok << 10) + k);
    ushort4 o;
    o.x = f2bf(v.x); o.y = f2bf(v.y); o.z = f2bf(v.z); o.w = f2bf(v.w);
    *reinterpret_cast<ushort4*>(X0 + (size_t)e4) = o;
}

// ---------------- fp32 -> bf16 bulk convert ----------------
__global__ void k_f32bf16(const float* __restrict__ s, u16* __restrict__ d, int n4) {
    int gid = blockIdx.x * blockDim.x + threadIdx.x;
    if (gid >= n4) return;
    float4 v = reinterpret_cast<const float4*>(s)[gid];
    ushort4 o;
    o.x = f2bf(v.x); o.y = f2bf(v.y); o.z = f2bf(v.z); o.w = f2bf(v.w);
    reinterpret_cast<ushort4*>(d)[gid] = o;
}

// ---------------- GEMM: C[M][N] = A[M][K] * B[N][K]^T + bias[N], bf16 in/out ----
__global__ __launch_bounds__(256) void k_gemm(const u16* __restrict__ A,
                                              const u16* __restrict__ B,
                                              const float* __restrict__ bias,
                                              u16* __restrict__ C,
                                              int M, int N, int K) {
    __shared__ __align__(16) u16 As[128 * 64];
    __shared__ __align__(16) u16 Bs[128 * 64];
    const int tid = threadIdx.x;
    const int lane = tid & 63, wid = tid >> 6;
    const int wm = wid >> 1, wn = wid & 1;
    const int m0 = blockIdx.y * 128, n0 = blockIdx.x * 128;
    const int lr = lane & 15, lk = lane >> 4;
    f32x4 zero = {0.f, 0.f, 0.f, 0.f};
    f32x4 acc[4][4];
    #pragma unroll
    for (int i = 0; i < 4; ++i)
        #pragma unroll
        for (int j = 0; j < 4; ++j) acc[i][j] = zero;

    for (int k0 = 0; k0 < K; k0 += 64) {
        #pragma unroll
        for (int r = 0; r < 4; ++r) {
            int c = wid * 4 + r;
            int o = c * 1024 + lane * 16;
            int row = o >> 7;
            int kb = o & 127;
            int kbs = kb ^ ((row & 7) << 4);
            const char* sa = (const char*)A + ((size_t)(m0 + row) * K + k0) * 2 + kbs;
            const char* sb = (const char*)B + ((size_t)(n0 + row) * K + k0) * 2 + kbs;
            __builtin_amdgcn_global_load_lds(GLP(sa), LDSP((char*)As + c * 1024), 16, 0, 0);
            __builtin_amdgcn_global_load_lds(GLP(sb), LDSP((char*)Bs + c * 1024), 16, 0, 0);
        }
        __syncthreads();
        #pragma unroll
        for (int kk = 0; kk < 2; ++kk) {
            bf16x8 af[4], bfr[4];
            #pragma unroll
            for (int i = 0; i < 4; ++i) {
                int rowA = wm * 64 + i * 16 + lr;
                int rowB = wn * 64 + i * 16 + lr;
                int kb = kk * 64 + lk * 16;
                af[i]  = *reinterpret_cast<const bf16x8*>((const char*)As + rowA * 128 + (kb ^ ((rowA & 7) << 4)));
                bfr[i] = *reinterpret_cast<const bf16x8*>((const char*)Bs + rowB * 128 + (kb ^ ((rowB & 7) << 4)));
            }
            #pragma unroll
            for (int i = 0; i < 4; ++i)
                #pragma unroll
                for (int j = 0; j < 4; ++j)
                    acc[i][j] = __builtin_amdgcn_mfma_f32_16x16x32_bf16(af[i], bfr[j], acc[i][j], 0, 0, 0);
        }
        __syncthreads();
    }
    #pragma unroll
    for (int j = 0; j < 4; ++j) {
        int col = n0 + wn * 64 + j * 16 + lr;
        float bv = bias[col];
        #pragma unroll
        for (int i = 0; i < 4; ++i) {
            int rowb = m0 + wm * 64 + i * 16 + lk * 4;
            #pragma unroll
            for (int q = 0; q < 4; ++q)
                C[(size_t)(rowb + q) * N + col] = f2bf(acc[i][j][q] + bv);
        }
    }
}

// ---------------- GRU layer scan, LLC-coherent sync (placement-free) ----------
// grid = 32 WGs: blockIdx>>4 = dir, &15 = j-slice (32 h-outputs each).
// h and flags exchanged via sc0sc1 (LLC write-through / LLC read) — no acquire
// fences, no cache invalidates, correct on any XCD placement. Spinners carry a
// 20us timeout that re-publishes their own flag via a release-agent atomic
// (R2-proven path, flushes L2 as a side effect) -> cannot hang, cannot be wrong.
__global__ __launch_bounds__(384) void k_gru(const u16* __restrict__ Gi,   // [16384][3072]
                                             const u16* __restrict__ Whh,  // [3072][512]
                                             const float* __restrict__ bhh,// [3072]
                                             u16* __restrict__ hbuf,       // [2][2][32][512]
                                             u16* __restrict__ X1,
                                             float* __restrict__ hid,
                                             float* __restrict__ outp,
                                             int layer,
                                             u32* __restrict__ flags) {    // [2][16][32]
    __shared__ float ghs[32][101];
    __shared__ __align__(16) u16 gis[32][104];
    __shared__ float bhh_s[96];
    const int tid = threadIdx.x;
    const int lane = tid & 63, w = tid >> 6;
    const int d = blockIdx.x >> 4, wg = blockIdx.x & 15;
    const int j0 = wg * 32;
    const int g = w >> 1, joff = (w & 1) * 16;
    const int lr = lane & 15, lk = lane >> 4;

    if (tid < 96) {
        int g2 = tid >> 5, jj = tid & 31;
        bhh_s[tid] = bhh[d * 1536 + g2 * 512 + j0 + jj];
    }
    // pin W_hh fragments (16 k-tiles x 4 VGPRs) in registers
    bf16x8 wf[16];
    {
        const u16* wr = Whh + (size_t)(d * 1536 + g * 512 + j0 + joff + lr) * 512 + lk * 8;
        #pragma unroll
        for (int kt = 0; kt < 16; ++kt)
            wf[kt] = *reinterpret_cast<const bf16x8*>(wr + kt * 32);
    }
    __syncthreads();

    const int p_nb = tid / 12, p_gc = tid % 12;
    const int p_lg = p_gc * 8;
    const int p_col = d * 1536 + (p_lg >> 5) * 512 + j0 + (p_lg & 31);
    const u32* myflags = flags + d * 16 * 32;
    u32* myflag = flags + (d * 16 + wg) * 32;

    float hp0 = 0.f, hp1 = 0.f, hp2 = 0.f;
    uint4 gv = *reinterpret_cast<const uint4*>(Gi + (size_t)p_nb * 3072 + p_col);

    for (int t = 0; t < 512; ++t) {
        if (t > 0) {
            if (tid < 16) {
                const u32* fp = myflags + tid * 32;
                long long tt0 = __builtin_amdgcn_s_memrealtime();   // 100 MHz
                while (ld_sc01_u32(fp) < (u32)t) {
                    __builtin_amdgcn_s_sleep(1);
                    if (__builtin_amdgcn_s_memrealtime() - tt0 > 2000) {  // 20 us
                        // backstop: heavy re-publish of MY flag (release flushes
                        // any of my stores stuck in L2; value is idempotent)
                        __hip_atomic_store(myflag, (u32)t, __ATOMIC_RELEASE,
                                           __HIP_MEMORY_SCOPE_AGENT);
                        tt0 = __builtin_amdgcn_s_memrealtime();
                    }
                }
            }
            __syncthreads();
        }

        // h(t-1) loads straight from LLC (fresh by flag ordering; no fence)
        const u16* hb = hbuf + ((size_t)d * 2 + ((t + 1) & 1)) * 16384;
        const u16* hr0 = hb + (size_t)lr * 512 + lk * 8;
        const u16* hr1 = hb + (size_t)(16 + lr) * 512 + lk * 8;
        bf16x8 a0[16], a1[16];
        #pragma unroll
        for (int kt = 0; kt < 16; ++kt) {
            asm volatile("global_load_dwordx4 %0, %1, off sc0 sc1"
                         : "=v"(a0[kt]) : "v"(hr0 + kt * 32));
            asm volatile("global_load_dwordx4 %0, %1, off sc0 sc1"
                         : "=v"(a1[kt]) : "v"(hr1 + kt * 32));
        }
        asm volatile("s_waitcnt vmcnt(0)" ::: "memory");
        __builtin_amdgcn_sched_barrier(0);
        f32x4 acc0 = {0.f, 0.f, 0.f, 0.f}, acc1 = acc0;
        #pragma unroll
        for (int kt = 0; kt < 16; ++kt) {
            acc0 = __builtin_amdgcn_mfma_f32_16x16x32_bf16(a0[kt], wf[kt], acc0, 0, 0, 0);
            acc1 = __builtin_amdgcn_mfma_f32_16x16x32_bf16(a1[kt], wf[kt], acc1, 0, 0, 0);
        }
        // prefetch gi for t+1 (plain cached load; L2 stays valid now)
        int tn = (t + 1 < 512) ? t + 1 : t;
        uint4 gv_next = *reinterpret_cast<const uint4*>(Gi + (size_t)(tn * 32 + p_nb) * 3072 + p_col);

        int colg = w * 16 + lr;
        float bv = bhh_s[colg];
        #pragma unroll
        for (int q = 0; q < 4; ++q) {
            ghs[lk * 4 + q][colg]      = acc0[q] + bv;
            ghs[16 + lk * 4 + q][colg] = acc1[q] + bv;
        }
        *reinterpret_cast<uint4*>(&gis[p_nb][p_lg]) = gv;
        __syncthreads();

        u16* hbw = hbuf + ((size_t)d * 2 + (t & 1)) * 16384;
        #pragma unroll
        for (int rep = 0; rep < 3; ++rep) {
            int e = tid + rep * 384;
            if (e < 1024) {
                int j = e & 31, nb = e >> 5;
                float gr = bf2f(gis[nb][j])      + ghs[nb][j];
                float gz = bf2f(gis[nb][32 + j]) + ghs[nb][32 + j];
                float r = 1.f / (1.f + __expf(-gr));
                float z = 1.f / (1.f + __expf(-gz));
                float ng = tanhf(bf2f(gis[nb][64 + j]) + r * ghs[nb][64 + j]);
                float hp = (rep == 0) ? hp0 : (rep == 1) ? hp1 : hp2;
                float hv = (1.f - z) * ng + z * hp;
                if (rep == 0) hp0 = hv; else if (rep == 1) hp1 = hv; else hp2 = hv;
                st_sc01_u16(hbw + (size_t)nb * 512 + j0 + j, f2bf(hv));  // LLC write-through
            }
        }
        asm volatile("s_waitcnt vmcnt(0)" ::: "memory");   // h stores acked at LLC
        __syncthreads();
        if (tid == 0)
            st_sc01_u32(myflag, (u32)(t + 1));

        // deferred output stores: drain behind next step's spin
        #pragma unroll
        for (int rep = 0; rep < 3; ++rep) {
            int e = tid + rep * 384;
            if (e < 1024) {
                int j = e & 31, nb = e >> 5;
                float hv = (rep == 0) ? hp0 : (rep == 1) ? hp1 : hp2;
                hid[((size_t)(t * 4 + layer * 2 + d) * 32 + nb) * 512 + j0 + j] = hv;
                if (layer == 0)
                    X1[((size_t)(t * 32 + nb)) * 1024 + (size_t)d * 512 + j0 + j] = f2bf(hv);
                else
                    outp[((size_t)nb * 512 + t) * 1024 + (size_t)d * 512 + j0 + j] = hv;
            }
        }
        gv = gv_next;
    }
}

extern "C" void kernel_launch(void* const* d_in, const int* in_sizes, int n_in,
                              void* d_out, int out_size, void* d_ws, size_t ws_size,
                              hipStream_t stream) {
    const int*   x    = (const int*)d_in[0];
    const float* emb  = (const float*)d_in[1];
    const float* w_ih = (const float*)d_in[2];
    const float* w_hh = (const float*)d_in[3];
    const float* b_ih = (const float*)d_in[4];
    const float* b_hh = (const float*)d_in[5];
    float* outp = (float*)d_out;
    float* hid  = outp + (size_t)32 * 512 * 1024;

    char* ws = (char*)d_ws;
    u16* X0     = (u16*)(ws);                  //  33,554,432 B
    u16* X1     = (u16*)(ws + 33554432);       //  33,554,432 B
    u16* Wih    = (u16*)(ws + 67108864);       //  12,582,912 B
    u16* Whh    = (u16*)(ws + 79691776);       //   6,291,456 B
    u16* Gi     = (u16*)(ws + 85983232);       // 100,663,296 B
    u16* hbuf0  = (u16*)(ws + 186646528);      //     131,072 B
    u16* hbuf1  = (u16*)(ws + 186777600);      //     131,072 B
    u32* flags0 = (u32*)(ws + 186908672);      //       4,096 B
    u32* flags1 = (u32*)(ws + 186912768);      //       4,096 B

    k_gather<<<16384, 256, 0, stream>>>(x, emb, X0);
    k_f32bf16<<<(1572864 + 255) / 256, 256, 0, stream>>>(w_ih, Wih, 1572864);
    k_f32bf16<<<( 786432 + 255) / 256, 256, 0, stream>>>(w_hh, Whh, 786432);

    // zero hbuf0|hbuf1|flags0|flags1 (contiguous)
    hipMemsetAsync(hbuf0, 0, 262144 + 8192, stream);

    // ---- layer 0 ----
    k_gemm<<<dim3(24, 128), 256, 0, stream>>>(X0, Wih, b_ih, Gi, 16384, 3072, 1024);
    k_gru<<<32, 384, 0, stream>>>(Gi, Whh, b_hh, hbuf0, X1, hid, outp, 0, flags0);

    // ---- layer 1 ----
    k_gemm<<<dim3(24, 128), 256, 0, stream>>>(X1, Wih + (size_t)3072 * 1024, b_ih + 3072,
                                              Gi, 16384, 3072, 1024);
    k_gru<<<32, 384, 0, stream>>>(Gi, Whh + (size_t)3072 * 512, b_hh + 3072, hbuf1,
                                  nullptr, hid, outp, 1, flags1);
}

// Round 5
// 4224.485 us; speedup vs baseline: 2.5322x; 1.9095x over previous
//
#include <hip/hip_runtime.h>
#include <hip/hip_bf16.h>

using u16 = unsigned short;
using u32 = unsigned int;
using bf16x8 = __attribute__((ext_vector_type(8))) __bf16;
using f32x4  = __attribute__((ext_vector_type(4))) float;

#define GLP(p) ((const __attribute__((address_space(1))) void*)(p))
#define LDSP(p) ((__attribute__((address_space(3))) void*)(p))

__device__ __forceinline__ float bf2f(u16 u) {
    union { float f; u32 i; } v; v.i = ((u32)u) << 16; return v.f;
}
__device__ __forceinline__ u16 f2bf(float f) {
    union { float f; u32 i; } v; v.f = f;
    u32 r = v.i + 0x7FFFu + ((v.i >> 16) & 1u);
    return (u16)(r >> 16);
}

// LLC-coherent primitives (bypass L1+L2; coherence point = LLC). Proven R4.
__device__ __forceinline__ u32 ld_sc01_u32(const u32* p) {
    u32 v;
    asm volatile("global_load_dword %0, %1, off sc0 sc1\n\ts_waitcnt vmcnt(0)"
                 : "=v"(v) : "v"(p) : "memory");
    return v;
}
__device__ __forceinline__ void st_sc01_u32(u32* p, u32 v) {
    asm volatile("global_store_dword %0, %1, off sc0 sc1" :: "v"(p), "v"(v) : "memory");
}
__device__ __forceinline__ void st_sc01_u16(u16* p, u16 v) {
    asm volatile("global_store_short %0, %1, off sc0 sc1" :: "v"(p), "v"(v) : "memory");
}

// ---------------- gather: X0[t*32+n][k] = bf16(emb[x[n][t]][k]) ----------------
__global__ void k_gather(const int* __restrict__ x, const float* __restrict__ emb,
                         u16* __restrict__ X0) {
    int gid = blockIdx.x * blockDim.x + threadIdx.x;
    if (gid >= 16384 * 256) return;
    int e4 = gid << 2;
    int m = e4 >> 10, k = e4 & 1023;
    int t = m >> 5, n = m & 31;
    int tok = x[n * 512 + t];
    float4 v = *reinterpret_cast<const float4*>(emb + ((size_t)tok << 10) + k);
    ushort4 o;
    o.x = f2bf(v.x); o.y = f2bf(v.y); o.z = f2bf(v.z); o.w = f2bf(v.w);
    *reinterpret_cast<ushort4*>(X0 + (size_t)e4) = o;
}

// ---------------- fp32 -> bf16 bulk convert ----------------
__global__ void k_f32bf16(const float* __restrict__ s, u16* __restrict__ d, int n4) {
    int gid = blockIdx.x * blockDim.x + threadIdx.x;
    if (gid >= n4) return;
    float4 v = reinterpret_cast<const float4*>(s)[gid];
    ushort4 o;
    o.x = f2bf(v.x); o.y = f2bf(v.y); o.z = f2bf(v.z); o.w = f2bf(v.w);
    reinterpret_cast<ushort4*>(d)[gid] = o;
}

// ---------------- GEMM (layer 0 gi, runs before the fused kernel) ----------
__global__ __launch_bounds__(256) void k_gemm(const u16* __restrict__ A,
                                              const u16* __restrict__ B,
                                              const float* __restrict__ bias,
                                              u16* __restrict__ C,
                                              int M, int N, int K) {
    __shared__ __align__(16) u16 As[128 * 64];
    __shared__ __align__(16) u16 Bs[128 * 64];
    const int tid = threadIdx.x;
    const int lane = tid & 63, wid = tid >> 6;
    const int wm = wid >> 1, wn = wid & 1;
    const int m0 = blockIdx.y * 128, n0 = blockIdx.x * 128;
    const int lr = lane & 15, lk = lane >> 4;
    f32x4 zero = {0.f, 0.f, 0.f, 0.f};
    f32x4 acc[4][4];
    #pragma unroll
    for (int i = 0; i < 4; ++i)
        #pragma unroll
        for (int j = 0; j < 4; ++j) acc[i][j] = zero;

    for (int k0 = 0; k0 < K; k0 += 64) {
        #pragma unroll
        for (int r = 0; r < 4; ++r) {
            int c = wid * 4 + r;
            int o = c * 1024 + lane * 16;
            int row = o >> 7;
            int kb = o & 127;
            int kbs = kb ^ ((row & 7) << 4);
            const char* sa = (const char*)A + ((size_t)(m0 + row) * K + k0) * 2 + kbs;
            const char* sb = (const char*)B + ((size_t)(n0 + row) * K + k0) * 2 + kbs;
            __builtin_amdgcn_global_load_lds(GLP(sa), LDSP((char*)As + c * 1024), 16, 0, 0);
            __builtin_amdgcn_global_load_lds(GLP(sb), LDSP((char*)Bs + c * 1024), 16, 0, 0);
        }
        __syncthreads();
        #pragma unroll
        for (int kk = 0; kk < 2; ++kk) {
            bf16x8 af[4], bfr[4];
            #pragma unroll
            for (int i = 0; i < 4; ++i) {
                int rowA = wm * 64 + i * 16 + lr;
                int rowB = wn * 64 + i * 16 + lr;
                int kb = kk * 64 + lk * 16;
                af[i]  = *reinterpret_cast<const bf16x8*>((const char*)As + rowA * 128 + (kb ^ ((rowA & 7) << 4)));
                bfr[i] = *reinterpret_cast<const bf16x8*>((const char*)Bs + rowB * 128 + (kb ^ ((rowB & 7) << 4)));
            }
            #pragma unroll
            for (int i = 0; i < 4; ++i)
                #pragma unroll
                for (int j = 0; j < 4; ++j)
                    acc[i][j] = __builtin_amdgcn_mfma_f32_16x16x32_bf16(af[i], bfr[j], acc[i][j], 0, 0, 0);
        }
        __syncthreads();
    }
    #pragma unroll
    for (int j = 0; j < 4; ++j) {
        int col = n0 + wn * 64 + j * 16 + lr;
        float bv = bias[col];
        #pragma unroll
        for (int i = 0; i < 4; ++i) {
            int rowb = m0 + wm * 64 + i * 16 + lk * 4;
            #pragma unroll
            for (int q = 0; q < 4; ++q)
                C[(size_t)(rowb + q) * N + col] = f2bf(acc[i][j][q] + bv);
        }
    }
}

// ---------------- GRU scan body (R4-proven core + pipeline hooks) ----------
// LAYER 0: plain gi loads; X1 stores sc01; xflag released after deferred stores.
// LAYER 1: gi loads sc01 (L2 holds stale layer-0 Gi lines), gated by gdone[t>>2].
template<int LAYER>
__device__ __forceinline__ void gru_body(char* smem, int d, int wg,
    const u16* __restrict__ Gi, const u16* __restrict__ Whh_l,
    const float* __restrict__ bhh_l, u16* __restrict__ hbuf,
    u16* __restrict__ X1, float* __restrict__ hid, float* __restrict__ outp,
    u32* __restrict__ flags, u32* __restrict__ xflags, const u32* __restrict__ gdone)
{
    float (*ghs)[101] = (float(*)[101])smem;                 // 12928 B
    u16 (*gis)[104]   = (u16(*)[104])(smem + 12928);         //  6656 B
    float* bhh_s      = (float*)(smem + 19584);              //   384 B
    const int tid = threadIdx.x;
    const int lane = tid & 63, w = tid >> 6;
    const int j0 = wg * 32;
    const int g = w >> 1, joff = (w & 1) * 16;
    const int lr = lane & 15, lk = lane >> 4;

    if (tid < 96) {
        int g2 = tid >> 5, jj = tid & 31;
        bhh_s[tid] = bhh_l[d * 1536 + g2 * 512 + j0 + jj];
    }
    bf16x8 wf[16];
    {
        const u16* wr = Whh_l + (size_t)(d * 1536 + g * 512 + j0 + joff + lr) * 512 + lk * 8;
        #pragma unroll
        for (int kt = 0; kt < 16; ++kt)
            wf[kt] = *reinterpret_cast<const bf16x8*>(wr + kt * 32);
    }
    if (LAYER == 1 && tid == 0) {   // gate gi block 0 (chaser sets gdone unconditionally)
        long long T0 = __builtin_amdgcn_s_memrealtime();
        while (ld_sc01_u32(&gdone[0]) == 0) {
            __builtin_amdgcn_s_sleep(4);
            if (__builtin_amdgcn_s_memrealtime() - T0 > 2000000) break;  // 20 ms
        }
    }
    __syncthreads();

    const int p_nb = tid / 12, p_gc = tid % 12;
    const int p_lg = p_gc * 8;
    const int p_col = d * 1536 + (p_lg >> 5) * 512 + j0 + (p_lg & 31);
    const u32* myflags = flags + d * 16 * 32;
    u32* myflag  = flags  + (d * 16 + wg) * 32;
    u32* myxflag = (LAYER == 0) ? xflags + (d * 16 + wg) * 32 : nullptr;

    float hp0 = 0.f, hp1 = 0.f, hp2 = 0.f;
    uint4 gv0;
    if (LAYER == 0)
        gv0 = *reinterpret_cast<const uint4*>(Gi + (size_t)p_nb * 3072 + p_col);

    for (int t = 0; t < 512; ++t) {
        if (t > 0) {
            if (tid < 16) {
                const u32* fp = myflags + tid * 32;
                long long tt0 = __builtin_amdgcn_s_memrealtime();
                while (ld_sc01_u32(fp) < (u32)t) {
                    __builtin_amdgcn_s_sleep(1);
                    if (__builtin_amdgcn_s_memrealtime() - tt0 > 2000) {
                        __hip_atomic_store(myflag, (u32)t, __ATOMIC_RELEASE,
                                           __HIP_MEMORY_SCOPE_AGENT);
                        tt0 = __builtin_amdgcn_s_memrealtime();
                    }
                }
            } else if (LAYER == 1 && tid == 16) {
                long long tt0 = __builtin_amdgcn_s_memrealtime();
                while (ld_sc01_u32(&gdone[t >> 2]) == 0) {
                    __builtin_amdgcn_s_sleep(1);
                    if (__builtin_amdgcn_s_memrealtime() - tt0 > 2000000) break;
                }
            }
            __syncthreads();
        }

        // gi for step t (L1: sc01, issued with h-loads; one vmcnt covers all)
        uint4 gv;
        if (LAYER == 1) {
            const u16* gip = Gi + (size_t)(t * 32 + p_nb) * 3072 + p_col;
            asm volatile("global_load_dwordx4 %0, %1, off sc0 sc1" : "=v"(gv) : "v"(gip));
        }
        const u16* hb = hbuf + ((size_t)d * 2 + ((t + 1) & 1)) * 16384;
        const u16* hr0 = hb + (size_t)lr * 512 + lk * 8;
        const u16* hr1 = hb + (size_t)(16 + lr) * 512 + lk * 8;
        bf16x8 a0[16], a1[16];
        #pragma unroll
        for (int kt = 0; kt < 16; ++kt) {
            asm volatile("global_load_dwordx4 %0, %1, off sc0 sc1"
                         : "=v"(a0[kt]) : "v"(hr0 + kt * 32));
            asm volatile("global_load_dwordx4 %0, %1, off sc0 sc1"
                         : "=v"(a1[kt]) : "v"(hr1 + kt * 32));
        }
        asm volatile("s_waitcnt vmcnt(0)" ::: "memory");
        __builtin_amdgcn_sched_barrier(0);
        f32x4 acc0 = {0.f, 0.f, 0.f, 0.f}, acc1 = acc0;
        #pragma unroll
        for (int kt = 0; kt < 16; ++kt) {
            acc0 = __builtin_amdgcn_mfma_f32_16x16x32_bf16(a0[kt], wf[kt], acc0, 0, 0, 0);
            acc1 = __builtin_amdgcn_mfma_f32_16x16x32_bf16(a1[kt], wf[kt], acc1, 0, 0, 0);
        }
        int colg = w * 16 + lr;
        float bv = bhh_s[colg];
        #pragma unroll
        for (int q = 0; q < 4; ++q) {
            ghs[lk * 4 + q][colg]      = acc0[q] + bv;
            ghs[16 + lk * 4 + q][colg] = acc1[q] + bv;
        }
        *reinterpret_cast<uint4*>(&gis[p_nb][p_lg]) = (LAYER == 0) ? gv0 : gv;
        if (LAYER == 0) {   // prefetch next step's gi (plain, compiler-managed)
            int tn = (t + 1 < 512) ? t + 1 : t;
            gv0 = *reinterpret_cast<const uint4*>(Gi + (size_t)(tn * 32 + p_nb) * 3072 + p_col);
        }
        __syncthreads();

        u16* hbw = hbuf + ((size_t)d * 2 + (t & 1)) * 16384;
        #pragma unroll
        for (int rep = 0; rep < 3; ++rep) {
            int e = tid + rep * 384;
            if (e < 1024) {
                int j = e & 31, nb = e >> 5;
                float gr = bf2f(gis[nb][j])      + ghs[nb][j];
                float gz = bf2f(gis[nb][32 + j]) + ghs[nb][32 + j];
                float r = 1.f / (1.f + __expf(-gr));
                float z = 1.f / (1.f + __expf(-gz));
                float ng = tanhf(bf2f(gis[nb][64 + j]) + r * ghs[nb][64 + j]);
                float hp = (rep == 0) ? hp0 : (rep == 1) ? hp1 : hp2;
                float hv = (1.f - z) * ng + z * hp;
                if (rep == 0) hp0 = hv; else if (rep == 1) hp1 = hv; else hp2 = hv;
                st_sc01_u16(hbw + (size_t)nb * 512 + j0 + j, f2bf(hv));
            }
        }
        asm volatile("s_waitcnt vmcnt(0)" ::: "memory");   // h stores at LLC
        __syncthreads();
        if (tid == 0)
            st_sc01_u32(myflag, (u32)(t + 1));

        // deferred output stores (drain behind next step's spin)
        #pragma unroll
        for (int rep = 0; rep < 3; ++rep) {
            int e = tid + rep * 384;
            if (e < 1024) {
                int j = e & 31, nb = e >> 5;
                float hv = (rep == 0) ? hp0 : (rep == 1) ? hp1 : hp2;
                hid[((size_t)(t * 4 + LAYER * 2 + d) * 32 + nb) * 512 + j0 + j] = hv;
                if (LAYER == 0)
                    st_sc01_u16(X1 + ((size_t)(t * 32 + nb)) * 1024 + (size_t)d * 512 + j0 + j,
                                f2bf(hv));
                else
                    outp[((size_t)nb * 512 + t) * 1024 + (size_t)d * 512 + j0 + j] = hv;
            }
        }
        if (LAYER == 0) {
            asm volatile("s_waitcnt vmcnt(0)" ::: "memory");  // X1 at LLC
            __syncthreads();
            if (tid == 0)
                st_sc01_u32(myxflag, (u32)(t + 1));
        }
    }
}

// ---------------- chaser GEMM: Gi1 tiles (128x96) chasing gru0's xflags ------
// 96 WGs; WG w: x = w&31 (col tile), y = (w>>5) + 3k (row blocks, increasing).
// Tile y ready when all 32 xflags >= 4y+4. C stored sc01; per-y counter -> gdone.
__device__ __forceinline__ void chaser_body(char* smem, int w,
    const u16* __restrict__ X1, const u16* __restrict__ Wih1,
    const float* __restrict__ bih1, u16* __restrict__ Gi,
    const u32* __restrict__ xflags, u32* __restrict__ cnt, u32* __restrict__ gdone)
{
    u16* As = (u16*)smem;            // 16 KB: 128 rows x 64 k
    u16* Bs = (u16*)(smem + 16384);  // 12 KB:  96 rows x 64 k
    const int tid = threadIdx.x;
    const int lane = tid & 63, wid = tid >> 6;
    const int wm = wid & 1, wn = wid >> 1;      // 2 x 3 wave grid
    const int lr = lane & 15, lk = lane >> 4;
    const int x = w & 31, yg = w >> 5;

    for (int y = yg; y < 128; y += 3) {
        if (tid < 32) {
            const u32* fp = xflags + tid * 32;
            u32 target = 4u * (u32)y + 4u;
            long long T0 = __builtin_amdgcn_s_memrealtime();
            while (ld_sc01_u32(fp) < target) {
                __builtin_amdgcn_s_sleep(4);
                if (__builtin_amdgcn_s_memrealtime() - T0 > 2000000) break;  // 20 ms
            }
        }
        __syncthreads();

        f32x4 zero = {0.f, 0.f, 0.f, 0.f};
        f32x4 acc[4][2];
        #pragma unroll
        for (int i = 0; i < 4; ++i) { acc[i][0] = zero; acc[i][1] = zero; }

        for (int k0 = 0; k0 < 1024; k0 += 64) {
            #pragma unroll
            for (int r = 0; r < 5; ++r) {
                int c = wid * 5 + r;               // 0..29, use 0..27
                if (c < 16) {
                    int o = c * 1024 + lane * 16;
                    int row = o >> 7, kb = o & 127;
                    int kbs = kb ^ ((row & 7) << 4);
                    const char* s = (const char*)X1 + ((size_t)(y * 128 + row) * 1024 + k0) * 2 + kbs;
                    __builtin_amdgcn_global_load_lds(GLP(s), LDSP((char*)As + c * 1024), 16, 0, 0);
                } else if (c < 28) {
                    int c2 = c - 16;
                    int o = c2 * 1024 + lane * 16;
                    int row = o >> 7, kb = o & 127;
                    int kbs = kb ^ ((row & 7) << 4);
                    const char* s = (const char*)Wih1 + ((size_t)(x * 96 + row) * 1024 + k0) * 2 + kbs;
                    __builtin_amdgcn_global_load_lds(GLP(s), LDSP((char*)Bs + c2 * 1024), 16, 0, 0);
                }
            }
            __syncthreads();
            #pragma unroll
            for (int kk = 0; kk < 2; ++kk) {
                bf16x8 af[4], bfr[2];
                int kb = kk * 64 + lk * 16;
                #pragma unroll
                for (int i = 0; i < 4; ++i) {
                    int rowA = wm * 64 + i * 16 + lr;
                    af[i] = *reinterpret_cast<const bf16x8*>((const char*)As + rowA * 128 + (kb ^ ((rowA & 7) << 4)));
                }
                #pragma unroll
                for (int j = 0; j < 2; ++j) {
                    int rowB = wn * 32 + j * 16 + lr;
                    bfr[j] = *reinterpret_cast<const bf16x8*>((const char*)Bs + rowB * 128 + (kb ^ ((rowB & 7) << 4)));
                }
                #pragma unroll
                for (int i = 0; i < 4; ++i)
                    #pragma unroll
                    for (int j = 0; j < 2; ++j)
                        acc[i][j] = __builtin_amdgcn_mfma_f32_16x16x32_bf16(af[i], bfr[j], acc[i][j], 0, 0, 0);
            }
            __syncthreads();
        }
        // epilogue: bias + sc01 store into Gi (LLC-visible for gru1)
        #pragma unroll
        for (int j = 0; j < 2; ++j) {
            int col = x * 96 + wn * 32 + j * 16 + lr;
            float bv = bih1[col];
            #pragma unroll
            for (int i = 0; i < 4; ++i) {
                int rowb = y * 128 + wm * 64 + i * 16 + lk * 4;
                #pragma unroll
                for (int q = 0; q < 4; ++q)
                    st_sc01_u16(Gi + (size_t)(rowb + q) * 3072 + col, f2bf(acc[i][j][q] + bv));
            }
        }
        asm volatile("s_waitcnt vmcnt(0)" ::: "memory");
        __syncthreads();
        if (tid == 0) {
            u32 old = __hip_atomic_fetch_add(&cnt[y], 1u, __ATOMIC_RELAXED,
                                             __HIP_MEMORY_SCOPE_AGENT);
            if (old == 31u)
                st_sc01_u32(&gdone[y], 1u);
        }
    }
}

// ---------------- fused pipeline kernel: gru0 | chaser gemm1 | gru1 ---------
__global__ __launch_bounds__(384) void k_fused(
    const u16* __restrict__ Gi_r, u16* __restrict__ Gi_w,
    const u16* __restrict__ Whh, const float* __restrict__ bhh,
    u16* __restrict__ hbuf0, u16* __restrict__ hbuf1,
    u16* __restrict__ X1, const u16* __restrict__ Wih1, const float* __restrict__ bih1,
    float* __restrict__ hid, float* __restrict__ outp,
    u32* __restrict__ flags0, u32* __restrict__ flags1,
    u32* __restrict__ xflags, u32* __restrict__ cnt, u32* __restrict__ gdone)
{
    __shared__ __align__(16) char smem[28672];
    int bid = blockIdx.x;
    if (bid < 32) {
        gru_body<0>(smem, bid >> 4, bid & 15, Gi_r, Whh, bhh, hbuf0,
                    X1, hid, outp, flags0, xflags, nullptr);
    } else if (bid < 128) {
        chaser_body(smem, bid - 32, X1, Wih1, bih1, Gi_w, xflags, cnt, gdone);
    } else {
        int b = bid - 128;
        gru_body<1>(smem, b >> 4, b & 15, Gi_r, Whh + (size_t)3072 * 512, bhh + 3072,
                    hbuf1, nullptr, hid, outp, flags1, nullptr, gdone);
    }
}

extern "C" void kernel_launch(void* const* d_in, const int* in_sizes, int n_in,
                              void* d_out, int out_size, void* d_ws, size_t ws_size,
                              hipStream_t stream) {
    const int*   x    = (const int*)d_in[0];
    const float* emb  = (const float*)d_in[1];
    const float* w_ih = (const float*)d_in[2];
    const float* w_hh = (const float*)d_in[3];
    const float* b_ih = (const float*)d_in[4];
    const float* b_hh = (const float*)d_in[5];
    float* outp = (float*)d_out;
    float* hid  = outp + (size_t)32 * 512 * 1024;

    char* ws = (char*)d_ws;
    u16* X0     = (u16*)(ws);                  //  33,554,432 B
    u16* X1     = (u16*)(ws + 33554432);       //  33,554,432 B
    u16* Wih    = (u16*)(ws + 67108864);       //  12,582,912 B
    u16* Whh    = (u16*)(ws + 79691776);       //   6,291,456 B
    u16* Gi     = (u16*)(ws + 85983232);       // 100,663,296 B
    u16* hbuf0  = (u16*)(ws + 186646528);      //     131,072 B
    u16* hbuf1  = (u16*)(ws + 186777600);      //     131,072 B
    u32* flags0 = (u32*)(ws + 186908672);      //       4,096 B
    u32* flags1 = (u32*)(ws + 186912768);      //       4,096 B
    u32* xflags = (u32*)(ws + 186916864);      //       4,096 B
    u32* cnt    = (u32*)(ws + 186920960);      //         512 B
    u32* gdone  = (u32*)(ws + 186921472);      //         512 B

    k_gather<<<16384, 256, 0, stream>>>(x, emb, X0);
    k_f32bf16<<<(1572864 + 255) / 256, 256, 0, stream>>>(w_ih, Wih, 1572864);
    k_f32bf16<<<( 786432 + 255) / 256, 256, 0, stream>>>(w_hh, Whh, 786432);

    // zero hbuf0|hbuf1|flags0|flags1|xflags|cnt|gdone (contiguous span)
    hipMemsetAsync(hbuf0, 0, 275456, stream);

    // layer-0 gi GEMM (must fully precede the scan)
    k_gemm<<<dim3(24, 128), 256, 0, stream>>>(X0, Wih, b_ih, Gi, 16384, 3072, 1024);

    // fused pipeline: gru0 (32 WGs) | chaser gemm1 (96 WGs) | gru1 (32 WGs)
    k_fused<<<160, 384, 0, stream>>>(Gi, Gi, Whh, b_hh, hbuf0, hbuf1,
                                     X1, Wih + (size_t)3072 * 1024, b_ih + 3072,
                                     hid, outp, flags0, flags1, xflags, cnt, gdone);
}

// Round 6
// 2396.357 us; speedup vs baseline: 4.4639x; 1.7629x over previous
//
#include <hip/hip_runtime.h>
#include <hip/hip_bf16.h>

using u16 = unsigned short;
using u32 = unsigned int;
using bf16x8 = __attribute__((ext_vector_type(8))) __bf16;
using f32x4  = __attribute__((ext_vector_type(4))) float;

#define GLP(p) ((const __attribute__((address_space(1))) void*)(p))
#define LDSP(p) ((__attribute__((address_space(3))) void*)(p))

__device__ __forceinline__ float bf2f(u16 u) {
    union { float f; u32 i; } v; v.i = ((u32)u) << 16; return v.f;
}
__device__ __forceinline__ u16 f2bf(float f) {
    union { float f; u32 i; } v; v.f = f;
    u32 r = v.i + 0x7FFFu + ((v.i >> 16) & 1u);
    return (u16)(r >> 16);
}

// LLC-coherent primitives (bypass L1+L2; coherence point = LLC). Proven R4/R5.
__device__ __forceinline__ u32 ld_sc01_u32(const u32* p) {
    u32 v;
    asm volatile("global_load_dword %0, %1, off sc0 sc1\n\ts_waitcnt vmcnt(0)"
                 : "=v"(v) : "v"(p) : "memory");
    return v;
}
__device__ __forceinline__ void st_sc01_u32(u32* p, u32 v) {
    asm volatile("global_store_dword %0, %1, off sc0 sc1" :: "v"(p), "v"(v) : "memory");
}
__device__ __forceinline__ void st_sc01_u16(u16* p, u16 v) {
    asm volatile("global_store_short %0, %1, off sc0 sc1" :: "v"(p), "v"(v) : "memory");
}

// ---------------- gather: X0[t*32+n][k] = bf16(emb[x[n][t]][k]) ----------------
__global__ void k_gather(const int* __restrict__ x, const float* __restrict__ emb,
                         u16* __restrict__ X0) {
    int gid = blockIdx.x * blockDim.x + threadIdx.x;
    if (gid >= 16384 * 256) return;
    int e4 = gid << 2;
    int m = e4 >> 10, k = e4 & 1023;
    int t = m >> 5, n = m & 31;
    int tok = x[n * 512 + t];
    float4 v = *reinterpret_cast<const float4*>(emb + ((size_t)tok << 10) + k);
    ushort4 o;
    o.x = f2bf(v.x); o.y = f2bf(v.y); o.z = f2bf(v.z); o.w = f2bf(v.w);
    *reinterpret_cast<ushort4*>(X0 + (size_t)e4) = o;
}

// ---------------- fp32 -> bf16 bulk convert ----------------
__global__ void k_f32bf16(const float* __restrict__ s, u16* __restrict__ d, int n4) {
    int gid = blockIdx.x * blockDim.x + threadIdx.x;
    if (gid >= n4) return;
    float4 v = reinterpret_cast<const float4*>(s)[gid];
    ushort4 o;
    o.x = f2bf(v.x); o.y = f2bf(v.y); o.z = f2bf(v.z); o.w = f2bf(v.w);
    reinterpret_cast<ushort4*>(d)[gid] = o;
}

// ---------------- GEMM (layer 0 gi, runs before the fused kernel) ----------
__global__ __launch_bounds__(256) void k_gemm(const u16* __restrict__ A,
                                              const u16* __restrict__ B,
                                              const float* __restrict__ bias,
                                              u16* __restrict__ C,
                                              int M, int N, int K) {
    __shared__ __align__(16) u16 As[128 * 64];
    __shared__ __align__(16) u16 Bs[128 * 64];
    const int tid = threadIdx.x;
    const int lane = tid & 63, wid = tid >> 6;
    const int wm = wid >> 1, wn = wid & 1;
    const int m0 = blockIdx.y * 128, n0 = blockIdx.x * 128;
    const int lr = lane & 15, lk = lane >> 4;
    f32x4 zero = {0.f, 0.f, 0.f, 0.f};
    f32x4 acc[4][4];
    #pragma unroll
    for (int i = 0; i < 4; ++i)
        #pragma unroll
        for (int j = 0; j < 4; ++j) acc[i][j] = zero;

    for (int k0 = 0; k0 < K; k0 += 64) {
        #pragma unroll
        for (int r = 0; r < 4; ++r) {
            int c = wid * 4 + r;
            int o = c * 1024 + lane * 16;
            int row = o >> 7;
            int kb = o & 127;
            int kbs = kb ^ ((row & 7) << 4);
            const char* sa = (const char*)A + ((size_t)(m0 + row) * K + k0) * 2 + kbs;
            const char* sb = (const char*)B + ((size_t)(n0 + row) * K + k0) * 2 + kbs;
            __builtin_amdgcn_global_load_lds(GLP(sa), LDSP((char*)As + c * 1024), 16, 0, 0);
            __builtin_amdgcn_global_load_lds(GLP(sb), LDSP((char*)Bs + c * 1024), 16, 0, 0);
        }
        __syncthreads();
        #pragma unroll
        for (int kk = 0; kk < 2; ++kk) {
            bf16x8 af[4], bfr[4];
            #pragma unroll
            for (int i = 0; i < 4; ++i) {
                int rowA = wm * 64 + i * 16 + lr;
                int rowB = wn * 64 + i * 16 + lr;
                int kb = kk * 64 + lk * 16;
                af[i]  = *reinterpret_cast<const bf16x8*>((const char*)As + rowA * 128 + (kb ^ ((rowA & 7) << 4)));
                bfr[i] = *reinterpret_cast<const bf16x8*>((const char*)Bs + rowB * 128 + (kb ^ ((rowB & 7) << 4)));
            }
            #pragma unroll
            for (int i = 0; i < 4; ++i)
                #pragma unroll
                for (int j = 0; j < 4; ++j)
                    acc[i][j] = __builtin_amdgcn_mfma_f32_16x16x32_bf16(af[i], bfr[j], acc[i][j], 0, 0, 0);
        }
        __syncthreads();
    }
    #pragma unroll
    for (int j = 0; j < 4; ++j) {
        int col = n0 + wn * 64 + j * 16 + lr;
        float bv = bias[col];
        #pragma unroll
        for (int i = 0; i < 4; ++i) {
            int rowb = m0 + wm * 64 + i * 16 + lk * 4;
            #pragma unroll
            for (int q = 0; q < 4; ++q)
                C[(size_t)(rowb + q) * N + col] = f2bf(acc[i][j][q] + bv);
        }
    }
}

// ---------------- GRU scan body: 8 WGs/dir x 768 threads, LDS-staged h -------
// Each WG owns 64 j-columns (192 gate rows = 12 waves x 16). h is staged once
// per WG into swizzled LDS (32 KB), cutting LLC read volume 12x vs R4/R5.
template<int LAYER>
__device__ __forceinline__ void gru_body(char* smem, int d, int wg,
    const u16* __restrict__ Gi, const u16* __restrict__ Whh_l,
    const float* __restrict__ bhh_l, u16* __restrict__ hbuf,
    u16* __restrict__ X1, float* __restrict__ hid, float* __restrict__ outp,
    u32* __restrict__ flags, u32* __restrict__ xflags, const u32* __restrict__ gdone)
{
    char* hS          = smem;                                // 32768 B (swizzled h)
    float (*ghs)[196] = (float(*)[196])(smem + 32768);       // 25088 B
    u16 (*gis)[208]   = (u16(*)[208])(smem + 57856);         // 13312 B
    float* bhh_s      = (float*)(smem + 71168);              //   768 B
    const int tid = threadIdx.x;
    const int lane = tid & 63, w = tid >> 6;                 // w in [0,12)
    const int j0 = wg * 64;
    const int g = w >> 2, joff = (w & 3) * 16;               // gate, j sub-block
    const int lr = lane & 15, lk = lane >> 4;

    if (tid < 192) {
        int g2 = tid >> 6, jj = tid & 63;
        bhh_s[tid] = bhh_l[d * 1536 + g2 * 512 + j0 + jj];
    }
    // pin W_hh fragments (16 k-tiles x 4 VGPRs = 64 VGPR/thread)
    bf16x8 wf[16];
    {
        const u16* wr = Whh_l + (size_t)(d * 1536 + g * 512 + j0 + joff + lr) * 512 + lk * 8;
        #pragma unroll
        for (int kt = 0; kt < 16; ++kt)
            wf[kt] = *reinterpret_cast<const bf16x8*>(wr + kt * 32);
    }
    if (LAYER == 1 && tid == 0) {
        long long T0 = __builtin_amdgcn_s_memrealtime();
        while (ld_sc01_u32(&gdone[0]) == 0) {
            __builtin_amdgcn_s_sleep(4);
            if (__builtin_amdgcn_s_memrealtime() - T0 > 2000000) break;  // 20 ms
        }
    }
    __syncthreads();

    // gi mapping: 768 threads x 16 B = 12 KB = 32 batches x 192 gates
    const int p_nb = tid / 24, p_gc = tid % 24;
    const int p_lg = p_gc * 8;
    const int p_col = d * 1536 + (p_lg >> 6) * 512 + j0 + (p_lg & 63);
    const u32* myflags = flags + d * 8 * 32;
    u32* myflag  = flags  + (d * 8 + wg) * 32;
    u32* myxflag = (LAYER == 0) ? xflags + (d * 8 + wg) * 32 : nullptr;

    float hp0 = 0.f, hp1 = 0.f, hp2 = 0.f;
    uint4 gv;
    if (LAYER == 0)
        gv = *reinterpret_cast<const uint4*>(Gi + (size_t)p_nb * 3072 + p_col);

    for (int t = 0; t < 512; ++t) {
        // ---- phase 1: wait for h(t-1) ----
        if (t > 0) {
            if (tid < 8) {
                const u32* fp = myflags + tid * 32;
                long long tt0 = __builtin_amdgcn_s_memrealtime();
                while (ld_sc01_u32(fp) < (u32)t) {
                    __builtin_amdgcn_s_sleep(1);
                    if (__builtin_amdgcn_s_memrealtime() - tt0 > 2000) {
                        __hip_atomic_store(myflag, (u32)t, __ATOMIC_RELEASE,
                                           __HIP_MEMORY_SCOPE_AGENT);
                        tt0 = __builtin_amdgcn_s_memrealtime();
                    }
                }
            } else if (LAYER == 1 && tid == 8) {
                long long tt0 = __builtin_amdgcn_s_memrealtime();
                while (ld_sc01_u32(&gdone[t >> 2]) == 0) {
                    __builtin_amdgcn_s_sleep(1);
                    if (__builtin_amdgcn_s_memrealtime() - tt0 > 2000000) break;
                }
            }
            __syncthreads();
        }

        // ---- phase 2: stage h (and layer-1 gi) from LLC into LDS ----
        const u16* hb = hbuf + ((size_t)d * 2 + ((t + 1) & 1)) * 16384;
        uint4 hv0, hv1, hv2;
        {
            int c0 = tid, c1 = tid + 768, c2 = tid + 1536;
            asm volatile("global_load_dwordx4 %0, %1, off sc0 sc1"
                         : "=v"(hv0) : "v"(hb + (size_t)(c0 >> 6) * 512 + (c0 & 63) * 8));
            asm volatile("global_load_dwordx4 %0, %1, off sc0 sc1"
                         : "=v"(hv1) : "v"(hb + (size_t)(c1 >> 6) * 512 + (c1 & 63) * 8));
            if (c2 < 2048)
                asm volatile("global_load_dwordx4 %0, %1, off sc0 sc1"
                             : "=v"(hv2) : "v"(hb + (size_t)(c2 >> 6) * 512 + (c2 & 63) * 8));
        }
        if (LAYER == 1) {
            const u16* gip = Gi + (size_t)(t * 32 + p_nb) * 3072 + p_col;
            asm volatile("global_load_dwordx4 %0, %1, off sc0 sc1" : "=v"(gv) : "v"(gip));
        }
        asm volatile("s_waitcnt vmcnt(0)" ::: "memory");
        {
            int c0 = tid, c1 = tid + 768, c2 = tid + 1536;
            int r0 = c0 >> 6, r1 = c1 >> 6, r2 = c2 >> 6;
            *reinterpret_cast<uint4*>(hS + r0 * 1024 + (((c0 & 63) * 16) ^ ((r0 & 15) << 4))) = hv0;
            *reinterpret_cast<uint4*>(hS + r1 * 1024 + (((c1 & 63) * 16) ^ ((r1 & 15) << 4))) = hv1;
            if (c2 < 2048)
                *reinterpret_cast<uint4*>(hS + r2 * 1024 + (((c2 & 63) * 16) ^ ((r2 & 15) << 4))) = hv2;
        }
        *reinterpret_cast<uint4*>(&gis[p_nb][p_lg]) = gv;
        __syncthreads();

        // ---- phase 3: gh matvec from LDS-staged h ----
        f32x4 acc0 = {0.f, 0.f, 0.f, 0.f}, acc1 = acc0;
        #pragma unroll
        for (int ktb = 0; ktb < 4; ++ktb) {
            bf16x8 a0[4], a1[4];
            #pragma unroll
            for (int r = 0; r < 4; ++r) {
                int kt = ktb * 4 + r;
                int boff = (lk * 16 + kt * 64) ^ (lr << 4);   // (lr&15)==lr
                a0[r] = *reinterpret_cast<const bf16x8*>(hS + lr * 1024 + boff);
                a1[r] = *reinterpret_cast<const bf16x8*>(hS + (16 + lr) * 1024 + boff);
            }
            #pragma unroll
            for (int r = 0; r < 4; ++r) {
                acc0 = __builtin_amdgcn_mfma_f32_16x16x32_bf16(a0[r], wf[ktb * 4 + r], acc0, 0, 0, 0);
                acc1 = __builtin_amdgcn_mfma_f32_16x16x32_bf16(a1[r], wf[ktb * 4 + r], acc1, 0, 0, 0);
            }
        }
        int colg = w * 16 + lr;                               // g*64 + joff + lr
        float bv = bhh_s[colg];
        #pragma unroll
        for (int q = 0; q < 4; ++q) {
            ghs[lk * 4 + q][colg]      = acc0[q] + bv;
            ghs[16 + lk * 4 + q][colg] = acc1[q] + bv;
        }
        if (LAYER == 0) {   // prefetch next step's gi (plain cached)
            int tn = (t + 1 < 512) ? t + 1 : t;
            gv = *reinterpret_cast<const uint4*>(Gi + (size_t)(tn * 32 + p_nb) * 3072 + p_col);
        }
        __syncthreads();

        // ---- phase 4: gates + h' ----
        u16* hbw = hbuf + ((size_t)d * 2 + (t & 1)) * 16384;
        #pragma unroll
        for (int rep = 0; rep < 3; ++rep) {
            int e = tid + rep * 768;
            if (e < 2048) {
                int j = e & 63, nb = e >> 6;
                float gr = bf2f(gis[nb][j])       + ghs[nb][j];
                float gz = bf2f(gis[nb][64 + j])  + ghs[nb][64 + j];
                float r = 1.f / (1.f + __expf(-gr));
                float z = 1.f / (1.f + __expf(-gz));
                float ng = tanhf(bf2f(gis[nb][128 + j]) + r * ghs[nb][128 + j]);
                float hp = (rep == 0) ? hp0 : (rep == 1) ? hp1 : hp2;
                float hv = (1.f - z) * ng + z * hp;
                if (rep == 0) hp0 = hv; else if (rep == 1) hp1 = hv; else hp2 = hv;
                st_sc01_u16(hbw + (size_t)nb * 512 + j0 + j, f2bf(hv));
            }
        }
        asm volatile("s_waitcnt vmcnt(0)" ::: "memory");   // h stores acked at LLC
        __syncthreads();
        if (tid == 0)
            st_sc01_u32(myflag, (u32)(t + 1));

        // ---- phase 5: deferred output stores (drain behind next spin) ----
        #pragma unroll
        for (int rep = 0; rep < 3; ++rep) {
            int e = tid + rep * 768;
            if (e < 2048) {
                int j = e & 63, nb = e >> 6;
                float hv = (rep == 0) ? hp0 : (rep == 1) ? hp1 : hp2;
                hid[((size_t)(t * 4 + LAYER * 2 + d) * 32 + nb) * 512 + j0 + j] = hv;
                if (LAYER == 0)
                    st_sc01_u16(X1 + ((size_t)(t * 32 + nb)) * 1024 + (size_t)d * 512 + j0 + j,
                                f2bf(hv));
                else
                    outp[((size_t)nb * 512 + t) * 1024 + (size_t)d * 512 + j0 + j] = hv;
            }
        }
        if (LAYER == 0) {
            asm volatile("s_waitcnt vmcnt(0)" ::: "memory");  // X1 at LLC
            __syncthreads();
            if (tid == 0)
                st_sc01_u32(myxflag, (u32)(t + 1));
        }
    }
}

// ---------------- chaser GEMM (waves 0-5 active; 6-11 idle behind guards) ----
__device__ __forceinline__ void chaser_body(char* smem, int w,
    const u16* __restrict__ X1, const u16* __restrict__ Wih1,
    const float* __restrict__ bih1, u16* __restrict__ Gi,
    const u32* __restrict__ xflags, u32* __restrict__ cnt, u32* __restrict__ gdone)
{
    u16* As = (u16*)smem;            // 16 KB
    u16* Bs = (u16*)(smem + 16384);  // 12 KB
    const int tid = threadIdx.x;
    const int lane = tid & 63, wid = tid >> 6;
    const int wm = wid & 1, wn = wid >> 1;
    const int lr = lane & 15, lk = lane >> 4;
    const int x = w & 31, yg = w >> 5;

    for (int y = yg; y < 128; y += 3) {
        if (tid < 16) {   // gru0 now has 16 xflags total ([2][8])
            const u32* fp = xflags + tid * 32;
            u32 target = 4u * (u32)y + 4u;
            long long T0 = __builtin_amdgcn_s_memrealtime();
            while (ld_sc01_u32(fp) < target) {
                __builtin_amdgcn_s_sleep(4);
                if (__builtin_amdgcn_s_memrealtime() - T0 > 2000000) break;  // 20 ms
            }
        }
        __syncthreads();

        f32x4 zero = {0.f, 0.f, 0.f, 0.f};
        f32x4 acc[4][2];
        #pragma unroll
        for (int i = 0; i < 4; ++i) { acc[i][0] = zero; acc[i][1] = zero; }

        for (int k0 = 0; k0 < 1024; k0 += 64) {
            #pragma unroll
            for (int r = 0; r < 5; ++r) {
                int c = wid * 5 + r;               // wid>=6 -> c>=30 -> skipped
                if (c < 16) {
                    int o = c * 1024 + lane * 16;
                    int row = o >> 7, kb = o & 127;
                    int kbs = kb ^ ((row & 7) << 4);
                    const char* s = (const char*)X1 + ((size_t)(y * 128 + row) * 1024 + k0) * 2 + kbs;
                    __builtin_amdgcn_global_load_lds(GLP(s), LDSP((char*)As + c * 1024), 16, 0, 0);
                } else if (c < 28) {
                    int c2 = c - 16;
                    int o = c2 * 1024 + lane * 16;
                    int row = o >> 7, kb = o & 127;
                    int kbs = kb ^ ((row & 7) << 4);
                    const char* s = (const char*)Wih1 + ((size_t)(x * 96 + row) * 1024 + k0) * 2 + kbs;
                    __builtin_amdgcn_global_load_lds(GLP(s), LDSP((char*)Bs + c2 * 1024), 16, 0, 0);
                }
            }
            __syncthreads();
            if (wid < 6) {
                #pragma unroll
                for (int kk = 0; kk < 2; ++kk) {
                    bf16x8 af[4], bfr[2];
                    int kb = kk * 64 + lk * 16;
                    #pragma unroll
                    for (int i = 0; i < 4; ++i) {
                        int rowA = wm * 64 + i * 16 + lr;
                        af[i] = *reinterpret_cast<const bf16x8*>((const char*)As + rowA * 128 + (kb ^ ((rowA & 7) << 4)));
                    }
                    #pragma unroll
                    for (int j = 0; j < 2; ++j) {
                        int rowB = wn * 32 + j * 16 + lr;
                        bfr[j] = *reinterpret_cast<const bf16x8*>((const char*)Bs + rowB * 128 + (kb ^ ((rowB & 7) << 4)));
                    }
                    #pragma unroll
                    for (int i = 0; i < 4; ++i)
                        #pragma unroll
                        for (int j = 0; j < 2; ++j)
                            acc[i][j] = __builtin_amdgcn_mfma_f32_16x16x32_bf16(af[i], bfr[j], acc[i][j], 0, 0, 0);
                }
            }
            __syncthreads();
        }
        if (wid < 6) {
            #pragma unroll
            for (int j = 0; j < 2; ++j) {
                int col = x * 96 + wn * 32 + j * 16 + lr;
                float bv = bih1[col];
                #pragma unroll
                for (int i = 0; i < 4; ++i) {
                    int rowb = y * 128 + wm * 64 + i * 16 + lk * 4;
                    #pragma unroll
                    for (int q = 0; q < 4; ++q)
                        st_sc01_u16(Gi + (size_t)(rowb + q) * 3072 + col, f2bf(acc[i][j][q] + bv));
                }
            }
        }
        asm volatile("s_waitcnt vmcnt(0)" ::: "memory");
        __syncthreads();
        if (tid == 0) {
            u32 old = __hip_atomic_fetch_add(&cnt[y], 1u, __ATOMIC_RELAXED,
                                             __HIP_MEMORY_SCOPE_AGENT);
            if (old == 31u)
                st_sc01_u32(&gdone[y], 1u);
        }
    }
}

// ---------------- fused pipeline: gru0 (16) | chaser (96) | gru1 (16) --------
__global__ __launch_bounds__(768, 3) void k_fused(
    const u16* __restrict__ Gi_r, u16* __restrict__ Gi_w,
    const u16* __restrict__ Whh, const float* __restrict__ bhh,
    u16* __restrict__ hbuf0, u16* __restrict__ hbuf1,
    u16* __restrict__ X1, const u16* __restrict__ Wih1, const float* __restrict__ bih1,
    float* __restrict__ hid, float* __restrict__ outp,
    u32* __restrict__ flags0, u32* __restrict__ flags1,
    u32* __restrict__ xflags, u32* __restrict__ cnt, u32* __restrict__ gdone)
{
    __shared__ __align__(16) char smem[71936];
    int bid = blockIdx.x;
    if (bid < 16) {
        gru_body<0>(smem, bid >> 3, bid & 7, Gi_r, Whh, bhh, hbuf0,
                    X1, hid, outp, flags0, xflags, nullptr);
    } else if (bid < 112) {
        chaser_body(smem, bid - 16, X1, Wih1, bih1, Gi_w, xflags, cnt, gdone);
    } else {
        int b = bid - 112;
        gru_body<1>(smem, b >> 3, b & 7, Gi_r, Whh + (size_t)3072 * 512, bhh + 3072,
                    hbuf1, nullptr, hid, outp, flags1, nullptr, gdone);
    }
}

extern "C" void kernel_launch(void* const* d_in, const int* in_sizes, int n_in,
                              void* d_out, int out_size, void* d_ws, size_t ws_size,
                              hipStream_t stream) {
    const int*   x    = (const int*)d_in[0];
    const float* emb  = (const float*)d_in[1];
    const float* w_ih = (const float*)d_in[2];
    const float* w_hh = (const float*)d_in[3];
    const float* b_ih = (const float*)d_in[4];
    const float* b_hh = (const float*)d_in[5];
    float* outp = (float*)d_out;
    float* hid  = outp + (size_t)32 * 512 * 1024;

    char* ws = (char*)d_ws;
    u16* X0     = (u16*)(ws);                  //  33,554,432 B
    u16* X1     = (u16*)(ws + 33554432);       //  33,554,432 B
    u16* Wih    = (u16*)(ws + 67108864);       //  12,582,912 B
    u16* Whh    = (u16*)(ws + 79691776);       //   6,291,456 B
    u16* Gi     = (u16*)(ws + 85983232);       // 100,663,296 B
    u16* hbuf0  = (u16*)(ws + 186646528);      //     131,072 B
    u16* hbuf1  = (u16*)(ws + 186777600);      //     131,072 B
    u32* flags0 = (u32*)(ws + 186908672);      //       2,048 B  [2][8][32]
    u32* flags1 = (u32*)(ws + 186910720);      //       2,048 B
    u32* xflags = (u32*)(ws + 186912768);      //       2,048 B  [2][8][32]
    u32* cnt    = (u32*)(ws + 186914816);      //         512 B
    u32* gdone  = (u32*)(ws + 186915328);      //         512 B

    k_gather<<<16384, 256, 0, stream>>>(x, emb, X0);
    k_f32bf16<<<(1572864 + 255) / 256, 256, 0, stream>>>(w_ih, Wih, 1572864);
    k_f32bf16<<<( 786432 + 255) / 256, 256, 0, stream>>>(w_hh, Whh, 786432);

    // zero hbuf0|hbuf1|flags0|flags1|xflags|cnt|gdone (contiguous span)
    hipMemsetAsync(hbuf0, 0, 269312, stream);

    // layer-0 gi GEMM (must fully precede the fused pipeline)
    k_gemm<<<dim3(24, 128), 256, 0, stream>>>(X0, Wih, b_ih, Gi, 16384, 3072, 1024);

    // fused pipeline: gru0 (16 WGs) | chaser gemm1 (96 WGs) | gru1 (16 WGs)
    k_fused<<<128, 768, 0, stream>>>(Gi, Gi, Whh, b_hh, hbuf0, hbuf1,
                                     X1, Wih + (size_t)3072 * 1024, b_ih + 3072,
                                     hid, outp, flags0, flags1, xflags, cnt, gdone);
}

// Round 8
// 2270.580 us; speedup vs baseline: 4.7112x; 1.0554x over previous
//
#include <hip/hip_runtime.h>
#include <hip/hip_bf16.h>

using u16 = unsigned short;
using u32 = unsigned int;
using bf16x8 = __attribute__((ext_vector_type(8))) __bf16;
using f32x4  = __attribute__((ext_vector_type(4))) float;
using u32x4  = __attribute__((ext_vector_type(4))) u32;

#define GLP(p) ((const __attribute__((address_space(1))) void*)(p))
#define LDSP(p) ((__attribute__((address_space(3))) void*)(p))

__device__ __forceinline__ float bf2f(u16 u) {
    union { float f; u32 i; } v; v.i = ((u32)u) << 16; return v.f;
}
__device__ __forceinline__ u16 f2bf(float f) {
    union { float f; u32 i; } v; v.f = f;
    u32 r = v.i + 0x7FFFu + ((v.i >> 16) & 1u);
    return (u16)(r >> 16);
}

// LLC-coherent primitives (bypass L1+L2; coherence point = LLC). Proven R4-R6.
__device__ __forceinline__ u32 ld_sc01_u32(const u32* p) {
    u32 v;
    asm volatile("global_load_dword %0, %1, off sc0 sc1\n\ts_waitcnt vmcnt(0)"
                 : "=v"(v) : "v"(p) : "memory");
    return v;
}
__device__ __forceinline__ void st_sc01_u32(u32* p, u32 v) {
    asm volatile("global_store_dword %0, %1, off sc0 sc1" :: "v"(p), "v"(v) : "memory");
}
__device__ __forceinline__ void st_sc01_u16(u16* p, u16 v) {
    asm volatile("global_store_short %0, %1, off sc0 sc1" :: "v"(p), "v"(v) : "memory");
}
__device__ __forceinline__ void st_sc01_u32x4(u16* p, u32x4 v) {
    asm volatile("global_store_dwordx4 %0, %1, off sc0 sc1" :: "v"(p), "v"(v) : "memory");
}

// ---------------- gather: X0[t*32+n][k] = bf16(emb[x[n][t]][k]) ----------------
__global__ void k_gather(const int* __restrict__ x, const float* __restrict__ emb,
                         u16* __restrict__ X0) {
    int gid = blockIdx.x * blockDim.x + threadIdx.x;
    if (gid >= 16384 * 256) return;
    int e4 = gid << 2;
    int m = e4 >> 10, k = e4 & 1023;
    int t = m >> 5, n = m & 31;
    int tok = x[n * 512 + t];
    float4 v = *reinterpret_cast<const float4*>(emb + ((size_t)tok << 10) + k);
    ushort4 o;
    o.x = f2bf(v.x); o.y = f2bf(v.y); o.z = f2bf(v.z); o.w = f2bf(v.w);
    *reinterpret_cast<ushort4*>(X0 + (size_t)e4) = o;
}

// ---------------- fp32 -> bf16 bulk convert ----------------
__global__ void k_f32bf16(const float* __restrict__ s, u16* __restrict__ d, int n4) {
    int gid = blockIdx.x * blockDim.x + threadIdx.x;
    if (gid >= n4) return;
    float4 v = reinterpret_cast<const float4*>(s)[gid];
    ushort4 o;
    o.x = f2bf(v.x); o.y = f2bf(v.y); o.z = f2bf(v.z); o.w = f2bf(v.w);
    reinterpret_cast<ushort4*>(d)[gid] = o;
}

// ---------------- GEMM (layer 0 gi, runs before the fused kernel) ----------
__global__ __launch_bounds__(256) void k_gemm(const u16* __restrict__ A,
                                              const u16* __restrict__ B,
                                              const float* __restrict__ bias,
                                              u16* __restrict__ C,
                                              int M, int N, int K) {
    __shared__ __align__(16) u16 As[128 * 64];
    __shared__ __align__(16) u16 Bs[128 * 64];
    const int tid = threadIdx.x;
    const int lane = tid & 63, wid = tid >> 6;
    const int wm = wid >> 1, wn = wid & 1;
    const int m0 = blockIdx.y * 128, n0 = blockIdx.x * 128;
    const int lr = lane & 15, lk = lane >> 4;
    f32x4 zero = {0.f, 0.f, 0.f, 0.f};
    f32x4 acc[4][4];
    #pragma unroll
    for (int i = 0; i < 4; ++i)
        #pragma unroll
        for (int j = 0; j < 4; ++j) acc[i][j] = zero;

    for (int k0 = 0; k0 < K; k0 += 64) {
        #pragma unroll
        for (int r = 0; r < 4; ++r) {
            int c = wid * 4 + r;
            int o = c * 1024 + lane * 16;
            int row = o >> 7;
            int kb = o & 127;
            int kbs = kb ^ ((row & 7) << 4);
            const char* sa = (const char*)A + ((size_t)(m0 + row) * K + k0) * 2 + kbs;
            const char* sb = (const char*)B + ((size_t)(n0 + row) * K + k0) * 2 + kbs;
            __builtin_amdgcn_global_load_lds(GLP(sa), LDSP((char*)As + c * 1024), 16, 0, 0);
            __builtin_amdgcn_global_load_lds(GLP(sb), LDSP((char*)Bs + c * 1024), 16, 0, 0);
        }
        __syncthreads();
        #pragma unroll
        for (int kk = 0; kk < 2; ++kk) {
            bf16x8 af[4], bfr[4];
            #pragma unroll
            for (int i = 0; i < 4; ++i) {
                int rowA = wm * 64 + i * 16 + lr;
                int rowB = wn * 64 + i * 16 + lr;
                int kb = kk * 64 + lk * 16;
                af[i]  = *reinterpret_cast<const bf16x8*>((const char*)As + rowA * 128 + (kb ^ ((rowA & 7) << 4)));
                bfr[i] = *reinterpret_cast<const bf16x8*>((const char*)Bs + rowB * 128 + (kb ^ ((rowB & 7) << 4)));
            }
            #pragma unroll
            for (int i = 0; i < 4; ++i)
                #pragma unroll
                for (int j = 0; j < 4; ++j)
                    acc[i][j] = __builtin_amdgcn_mfma_f32_16x16x32_bf16(af[i], bfr[j], acc[i][j], 0, 0, 0);
        }
        __syncthreads();
    }
    #pragma unroll
    for (int j = 0; j < 4; ++j) {
        int col = n0 + wn * 64 + j * 16 + lr;
        float bv = bias[col];
        #pragma unroll
        for (int i = 0; i < 4; ++i) {
            int rowb = m0 + wm * 64 + i * 16 + lk * 4;
            #pragma unroll
            for (int q = 0; q < 4; ++q)
                C[(size_t)(rowb + q) * N + col] = f2bf(acc[i][j][q] + bv);
        }
    }
}

// ---------------- GRU scan body R7 ------------------------------------------
// 8 WGs/dir x 768 threads. Changes vs R6:
//  - staging split into batch-halves: acc0 MFMAs overlap rows-16..31 loads
//  - deferred output stores confined to tid>=512 (via hvS LDS); spinners clean
//  - flag released by tid16; xflag only every 4 steps (chaser granularity)
template<int LAYER>
__device__ __forceinline__ void gru_body(char* smem, int d, int wg,
    const u16* __restrict__ Gi, const u16* __restrict__ Whh_l,
    const float* __restrict__ bhh_l, u16* __restrict__ hbuf,
    u16* __restrict__ X1, float* __restrict__ hid, float* __restrict__ outp,
    u32* __restrict__ flags, u32* __restrict__ xflags, const u32* __restrict__ gdone)
{
    char* hS          = smem;                                // 32768 B (swizzled h)
    float (*ghs)[196] = (float(*)[196])(smem + 32768);       // 25088 B
    u16 (*gis)[208]   = (u16(*)[208])(smem + 57856);         // 13312 B
    float* bhh_s      = (float*)(smem + 71168);              //   768 B
    u16* hvS          = (u16*)(smem + 71936);                //  4096 B [32][64]
    const int tid = threadIdx.x;
    const int lane = tid & 63, w = tid >> 6;                 // w in [0,12)
    const int j0 = wg * 64;
    const int g = w >> 2, joff = (w & 3) * 16;
    const int lr = lane & 15, lk = lane >> 4;

    if (tid < 192) {
        int g2 = tid >> 6, jj = tid & 63;
        bhh_s[tid] = bhh_l[d * 1536 + g2 * 512 + j0 + jj];
    }
    // pin W_hh fragments (16 k-tiles x 4 VGPRs = 64 VGPR/thread)
    bf16x8 wf[16];
    {
        const u16* wr = Whh_l + (size_t)(d * 1536 + g * 512 + j0 + joff + lr) * 512 + lk * 8;
        #pragma unroll
        for (int kt = 0; kt < 16; ++kt)
            wf[kt] = *reinterpret_cast<const bf16x8*>(wr + kt * 32);
    }
    if (LAYER == 1 && tid == 0) {
        long long T0 = __builtin_amdgcn_s_memrealtime();
        while (ld_sc01_u32(&gdone[0]) == 0) {
            __builtin_amdgcn_s_sleep(4);
            if (__builtin_amdgcn_s_memrealtime() - T0 > 2000000) break;  // 20 ms
        }
    }
    __syncthreads();

    // gi mapping: 768 threads x 16 B = 12 KB = 32 batches x 192 gates
    const int p_nb = tid / 24, p_gc = tid % 24;
    const int p_lg = p_gc * 8;
    const int p_col = d * 1536 + (p_lg >> 6) * 512 + j0 + (p_lg & 63);
    const u32* myflags = flags + d * 8 * 32;
    u32* myflag  = flags  + (d * 8 + wg) * 32;
    u32* myxflag = (LAYER == 0) ? xflags + (d * 8 + wg) * 32 : nullptr;

    // stage-chunk geometry (tid<512): 4 x 16B chunks, rows r, r+8, r+16, r+24
    const int srow = tid >> 6;            // 0..7
    const int scol = (tid & 63) * 8;      // u16 offset in row
    const int scb  = (tid & 63) * 16;     // byte offset in row

    float hp0 = 0.f, hp1 = 0.f, hp2 = 0.f;
    uint4 gv;
    if (LAYER == 0)
        gv = *reinterpret_cast<const uint4*>(Gi + (size_t)p_nb * 3072 + p_col);

    for (int t = 0; t < 512; ++t) {
        // ---- B0: wait for h(t-1); spinners have empty VMEM queues ----
        if (t > 0) {
            if (tid < 8) {
                const u32* fp = myflags + tid * 32;
                long long tt0 = __builtin_amdgcn_s_memrealtime();
                while (ld_sc01_u32(fp) < (u32)t) {
                    __builtin_amdgcn_s_sleep(1);
                    if (__builtin_amdgcn_s_memrealtime() - tt0 > 2000) {
                        __hip_atomic_store(myflag, (u32)t, __ATOMIC_RELEASE,
                                           __HIP_MEMORY_SCOPE_AGENT);
                        tt0 = __builtin_amdgcn_s_memrealtime();
                    }
                }
            } else if (LAYER == 1 && tid == 8) {
                long long tt0 = __builtin_amdgcn_s_memrealtime();
                while (ld_sc01_u32(&gdone[t >> 2]) == 0) {
                    __builtin_amdgcn_s_sleep(1);
                    if (__builtin_amdgcn_s_memrealtime() - tt0 > 2000000) break;
                }
            }
            __syncthreads();
        }

        // ---- phase 2: issue all staged loads (batch halves A=rows0-15, B=16-31)
        const u16* hb = hbuf + ((size_t)d * 2 + ((t + 1) & 1)) * 16384;
        u32x4 va0, va1, vb0, vb1, gvv;
        if (tid < 512) {
            asm volatile("global_load_dwordx4 %0, %1, off sc0 sc1"
                         : "=v"(va0) : "v"(hb + (size_t)srow * 512 + scol));
            asm volatile("global_load_dwordx4 %0, %1, off sc0 sc1"
                         : "=v"(va1) : "v"(hb + (size_t)(srow + 8) * 512 + scol));
            asm volatile("global_load_dwordx4 %0, %1, off sc0 sc1"
                         : "=v"(vb0) : "v"(hb + (size_t)(srow + 16) * 512 + scol));
            asm volatile("global_load_dwordx4 %0, %1, off sc0 sc1"
                         : "=v"(vb1) : "v"(hb + (size_t)(srow + 24) * 512 + scol));
        }
        if (LAYER == 1) {
            const u16* gip = Gi + (size_t)(t * 32 + p_nb) * 3072 + p_col;
            asm volatile("global_load_dwordx4 %0, %1, off sc0 sc1" : "=v"(gvv) : "v"(gip));
        }
        // A-wait: retire the two A loads (tolerates a still-outstanding gv)
        if (tid < 512) {
            if (LAYER == 0) asm volatile("s_waitcnt vmcnt(2)" ::: "memory");
            else            asm volatile("s_waitcnt vmcnt(3)" ::: "memory");
            int r0 = srow, r1 = srow + 8;
            *reinterpret_cast<u32x4*>(hS + r0 * 1024 + (scb ^ ((r0 & 15) << 4))) = va0;
            *reinterpret_cast<u32x4*>(hS + r1 * 1024 + (scb ^ ((r1 & 15) << 4))) = va1;
        }
        __syncthreads();   // B1: rows 0-15 staged

        // ---- phase 3a: acc0 MFMAs (batches 0-15) while B loads fly ----
        f32x4 acc0 = {0.f, 0.f, 0.f, 0.f};
        #pragma unroll
        for (int kt = 0; kt < 16; ++kt) {
            int boff = (lk * 16 + kt * 64) ^ (lr << 4);
            bf16x8 a = *reinterpret_cast<const bf16x8*>(hS + lr * 1024 + boff);
            acc0 = __builtin_amdgcn_mfma_f32_16x16x32_bf16(a, wf[kt], acc0, 0, 0, 0);
        }
        if (tid < 512) {
            asm volatile("s_waitcnt vmcnt(0)" ::: "memory");
            int r2 = srow + 16, r3 = srow + 24;
            *reinterpret_cast<u32x4*>(hS + r2 * 1024 + (scb ^ ((r2 & 15) << 4))) = vb0;
            *reinterpret_cast<u32x4*>(hS + r3 * 1024 + (scb ^ ((r3 & 15) << 4))) = vb1;
        } else if (LAYER == 1) {
            asm volatile("s_waitcnt vmcnt(0)" ::: "memory");
        }
        if (LAYER == 0) {
            *reinterpret_cast<uint4*>(&gis[p_nb][p_lg]) = gv;
        } else {
            *reinterpret_cast<u32x4*>(&gis[p_nb][p_lg]) = gvv;
        }
        __syncthreads();   // B2: rows 16-31 staged

        // ---- phase 3b: acc1 MFMAs + ghs + next-gi prefetch ----
        f32x4 acc1 = {0.f, 0.f, 0.f, 0.f};
        #pragma unroll
        for (int kt = 0; kt < 16; ++kt) {
            int boff = (lk * 16 + kt * 64) ^ (lr << 4);
            bf16x8 a = *reinterpret_cast<const bf16x8*>(hS + (16 + lr) * 1024 + boff);
            acc1 = __builtin_amdgcn_mfma_f32_16x16x32_bf16(a, wf[kt], acc1, 0, 0, 0);
        }
        int colg = w * 16 + lr;
        float bv = bhh_s[colg];
        #pragma unroll
        for (int q = 0; q < 4; ++q) {
            ghs[lk * 4 + q][colg]      = acc0[q] + bv;
            ghs[16 + lk * 4 + q][colg] = acc1[q] + bv;
        }
        if (LAYER == 0) {
            int tn = (t + 1 < 512) ? t + 1 : t;
            gv = *reinterpret_cast<const uint4*>(Gi + (size_t)(tn * 32 + p_nb) * 3072 + p_col);
        }
        __syncthreads();   // B3

        // ---- phase 4: gates + h'; h -> global (sc01) + hvS (LDS) ----
        u16* hbw = hbuf + ((size_t)d * 2 + (t & 1)) * 16384;
        #pragma unroll
        for (int rep = 0; rep < 3; ++rep) {
            int e = tid + rep * 768;
            if (e < 2048) {
                int j = e & 63, nb = e >> 6;
                float gr = bf2f(gis[nb][j])       + ghs[nb][j];
                float gz = bf2f(gis[nb][64 + j])  + ghs[nb][64 + j];
                float r = 1.f / (1.f + __expf(-gr));
                float z = 1.f / (1.f + __expf(-gz));
                float ng = tanhf(bf2f(gis[nb][128 + j]) + r * ghs[nb][128 + j]);
                float hp = (rep == 0) ? hp0 : (rep == 1) ? hp1 : hp2;
                float hv = (1.f - z) * ng + z * hp;
                if (rep == 0) hp0 = hv; else if (rep == 1) hp1 = hv; else hp2 = hv;
                u16 hb16 = f2bf(hv);
                st_sc01_u16(hbw + (size_t)nb * 512 + j0 + j, hb16);
                hvS[nb * 64 + j] = hb16;
            }
        }
        asm volatile("s_waitcnt vmcnt(0)" ::: "memory");   // h stores acked at LLC
        __syncthreads();   // B4
        if (tid == 16)
            st_sc01_u32(myflag, (u32)(t + 1));

        // ---- phase 5: deferred outputs, tid>=512 only (spinners stay clean) --
        if (tid >= 512) {
            int q = tid - 512, nb = q >> 3, j8 = (q & 7) * 8;
            union { u32x4 v; u16 s[8]; } h8;
            h8.v = *reinterpret_cast<const u32x4*>(hvS + nb * 64 + j8);
            float f0 = bf2f(h8.s[0]), f1 = bf2f(h8.s[1]), f2 = bf2f(h8.s[2]), f3 = bf2f(h8.s[3]);
            float f4 = bf2f(h8.s[4]), f5 = bf2f(h8.s[5]), f6 = bf2f(h8.s[6]), f7 = bf2f(h8.s[7]);
            float* hp = hid + ((size_t)(t * 4 + LAYER * 2 + d) * 32 + nb) * 512 + j0 + j8;
            *reinterpret_cast<float4*>(hp)     = make_float4(f0, f1, f2, f3);
            *reinterpret_cast<float4*>(hp + 4) = make_float4(f4, f5, f6, f7);
            if (LAYER == 0) {
                u16* xp = X1 + (size_t)(t * 32 + nb) * 1024 + (size_t)d * 512 + j0 + j8;
                st_sc01_u32x4(xp, h8.v);
            } else {
                float* op = outp + ((size_t)nb * 512 + t) * 1024 + (size_t)d * 512 + j0 + j8;
                *reinterpret_cast<float4*>(op)     = make_float4(f0, f1, f2, f3);
                *reinterpret_cast<float4*>(op + 4) = make_float4(f4, f5, f6, f7);
            }
        }
        // xflag only at chaser granularity (every 4 steps)
        if (LAYER == 0 && (t & 3) == 3) {
            asm volatile("s_waitcnt vmcnt(0)" ::: "memory");  // X1 at LLC
            __syncthreads();
            if (tid == 17)
                st_sc01_u32(myxflag, (u32)(t + 1));
        }
    }
}

// ---------------- chaser GEMM (waves 0-5 active; 6-11 idle behind guards) ----
__device__ __forceinline__ void chaser_body(char* smem, int w,
    const u16* __restrict__ X1, const u16* __restrict__ Wih1,
    const float* __restrict__ bih1, u16* __restrict__ Gi,
    const u32* __restrict__ xflags, u32* __restrict__ cnt, u32* __restrict__ gdone)
{
    u16* As = (u16*)smem;            // 16 KB
    u16* Bs = (u16*)(smem + 16384);  // 12 KB
    const int tid = threadIdx.x;
    const int lane = tid & 63, wid = tid >> 6;
    const int wm = wid & 1, wn = wid >> 1;
    const int lr = lane & 15, lk = lane >> 4;
    const int x = w & 31, yg = w >> 5;

    for (int y = yg; y < 128; y += 3) {
        if (tid < 16) {
            const u32* fp = xflags + tid * 32;
            u32 target = 4u * (u32)y + 4u;
            long long T0 = __builtin_amdgcn_s_memrealtime();
            while (ld_sc01_u32(fp) < target) {
                __builtin_amdgcn_s_sleep(4);
                if (__builtin_amdgcn_s_memrealtime() - T0 > 2000000) break;  // 20 ms
            }
        }
        __syncthreads();

        f32x4 zero = {0.f, 0.f, 0.f, 0.f};
        f32x4 acc[4][2];
        #pragma unroll
        for (int i = 0; i < 4; ++i) { acc[i][0] = zero; acc[i][1] = zero; }

        for (int k0 = 0; k0 < 1024; k0 += 64) {
            #pragma unroll
            for (int r = 0; r < 5; ++r) {
                int c = wid * 5 + r;               // wid>=6 -> c>=30 -> skipped
                if (c < 16) {
                    int o = c * 1024 + lane * 16;
                    int row = o >> 7, kb = o & 127;
                    int kbs = kb ^ ((row & 7) << 4);
                    const char* s = (const char*)X1 + ((size_t)(y * 128 + row) * 1024 + k0) * 2 + kbs;
                    __builtin_amdgcn_global_load_lds(GLP(s), LDSP((char*)As + c * 1024), 16, 0, 0);
                } else if (c < 28) {
                    int c2 = c - 16;
                    int o = c2 * 1024 + lane * 16;
                    int row = o >> 7, kb = o & 127;
                    int kbs = kb ^ ((row & 7) << 4);
                    const char* s = (const char*)Wih1 + ((size_t)(x * 96 + row) * 1024 + k0) * 2 + kbs;
                    __builtin_amdgcn_global_load_lds(GLP(s), LDSP((char*)Bs + c2 * 1024), 16, 0, 0);
                }
            }
            __syncthreads();
            if (wid < 6) {
                #pragma unroll
                for (int kk = 0; kk < 2; ++kk) {
                    bf16x8 af[4], bfr[2];
                    int kb = kk * 64 + lk * 16;
                    #pragma unroll
                    for (int i = 0; i < 4; ++i) {
                        int rowA = wm * 64 + i * 16 + lr;
                        af[i] = *reinterpret_cast<const bf16x8*>((const char*)As + rowA * 128 + (kb ^ ((rowA & 7) << 4)));
                    }
                    #pragma unroll
                    for (int j = 0; j < 2; ++j) {
                        int rowB = wn * 32 + j * 16 + lr;
                        bfr[j] = *reinterpret_cast<const bf16x8*>((const char*)Bs + rowB * 128 + (kb ^ ((rowB & 7) << 4)));
                    }
                    #pragma unroll
                    for (int i = 0; i < 4; ++i)
                        #pragma unroll
                        for (int j = 0; j < 2; ++j)
                            acc[i][j] = __builtin_amdgcn_mfma_f32_16x16x32_bf16(af[i], bfr[j], acc[i][j], 0, 0, 0);
                }
            }
            __syncthreads();
        }
        if (wid < 6) {
            #pragma unroll
            for (int j = 0; j < 2; ++j) {
                int col = x * 96 + wn * 32 + j * 16 + lr;
                float bv = bih1[col];
                #pragma unroll
                for (int i = 0; i < 4; ++i) {
                    int rowb = y * 128 + wm * 64 + i * 16 + lk * 4;
                    #pragma unroll
                    for (int q = 0; q < 4; ++q)
                        st_sc01_u16(Gi + (size_t)(rowb + q) * 3072 + col, f2bf(acc[i][j][q] + bv));
                }
            }
        }
        asm volatile("s_waitcnt vmcnt(0)" ::: "memory");
        __syncthreads();
        if (tid == 0) {
            u32 old = __hip_atomic_fetch_add(&cnt[y], 1u, __ATOMIC_RELAXED,
                                             __HIP_MEMORY_SCOPE_AGENT);
            if (old == 31u)
                st_sc01_u32(&gdone[y], 1u);
        }
    }
}

// ---------------- fused pipeline: gru0 (16) | chaser (96) | gru1 (16) --------
__global__ __launch_bounds__(768, 3) void k_fused(
    const u16* __restrict__ Gi_r, u16* __restrict__ Gi_w,
    const u16* __restrict__ Whh, const float* __restrict__ bhh,
    u16* __restrict__ hbuf0, u16* __restrict__ hbuf1,
    u16* __restrict__ X1, const u16* __restrict__ Wih1, const float* __restrict__ bih1,
    float* __restrict__ hid, float* __restrict__ outp,
    u32* __restrict__ flags0, u32* __restrict__ flags1,
    u32* __restrict__ xflags, u32* __restrict__ cnt, u32* __restrict__ gdone)
{
    __shared__ __align__(16) char smem[76032];
    int bid = blockIdx.x;
    if (bid < 16) {
        gru_body<0>(smem, bid >> 3, bid & 7, Gi_r, Whh, bhh, hbuf0,
                    X1, hid, outp, flags0, xflags, nullptr);
    } else if (bid < 112) {
        chaser_body(smem, bid - 16, X1, Wih1, bih1, Gi_w, xflags, cnt, gdone);
    } else {
        int b = bid - 112;
        gru_body<1>(smem, b >> 3, b & 7, Gi_r, Whh + (size_t)3072 * 512, bhh + 3072,
                    hbuf1, nullptr, hid, outp, flags1, nullptr, gdone);
    }
}

extern "C" void kernel_launch(void* const* d_in, const int* in_sizes, int n_in,
                              void* d_out, int out_size, void* d_ws, size_t ws_size,
                              hipStream_t stream) {
    const int*   x    = (const int*)d_in[0];
    const float* emb  = (const float*)d_in[1];
    const float* w_ih = (const float*)d_in[2];
    const float* w_hh = (const float*)d_in[3];
    const float* b_ih = (const float*)d_in[4];
    const float* b_hh = (const float*)d_in[5];
    float* outp = (float*)d_out;
    float* hid  = outp + (size_t)32 * 512 * 1024;

    char* ws = (char*)d_ws;
    u16* X0     = (u16*)(ws);                  //  33,554,432 B
    u16* X1     = (u16*)(ws + 33554432);       //  33,554,432 B
    u16* Wih    = (u16*)(ws + 67108864);       //  12,582,912 B
    u16* Whh    = (u16*)(ws + 79691776);       //   6,291,456 B
    u16* Gi     = (u16*)(ws + 85983232);       // 100,663,296 B
    u16* hbuf0  = (u16*)(ws + 186646528);      //     131,072 B
    u16* hbuf1  = (u16*)(ws + 186777600);      //     131,072 B
    u32* flags0 = (u32*)(ws + 186908672);      //       2,048 B  [2][8][32]
    u32* flags1 = (u32*)(ws + 186910720);      //       2,048 B
    u32* xflags = (u32*)(ws + 186912768);      //       2,048 B  [2][8][32]
    u32* cnt    = (u32*)(ws + 186914816);      //         512 B
    u32* gdone  = (u32*)(ws + 186915328);      //         512 B

    k_gather<<<16384, 256, 0, stream>>>(x, emb, X0);
    k_f32bf16<<<(1572864 + 255) / 256, 256, 0, stream>>>(w_ih, Wih, 1572864);
    k_f32bf16<<<( 786432 + 255) / 256, 256, 0, stream>>>(w_hh, Whh, 786432);

    // zero hbuf0|hbuf1|flags0|flags1|xflags|cnt|gdone (contiguous span)
    (void)hipMemsetAsync(hbuf0, 0, 269312, stream);

    // layer-0 gi GEMM (must fully precede the fused pipeline)
    k_gemm<<<dim3(24, 128), 256, 0, stream>>>(X0, Wih, b_ih, Gi, 16384, 3072, 1024);

    // fused pipeline: gru0 (16 WGs) | chaser gemm1 (96 WGs) | gru1 (16 WGs)
    k_fused<<<128, 768, 0, stream>>>(Gi, Gi, Whh, b_hh, hbuf0, hbuf1,
                                     X1, Wih + (size_t)3072 * 1024, b_ih + 3072,
                                     hid, outp, flags0, flags1, xflags, cnt, gdone);
}

// Round 9
// 2141.539 us; speedup vs baseline: 4.9951x; 1.0603x over previous
//
#include <hip/hip_runtime.h>
#include <hip/hip_bf16.h>

using u16 = unsigned short;
using u32 = unsigned int;
using bf16x8 = __attribute__((ext_vector_type(8))) __bf16;
using f32x4  = __attribute__((ext_vector_type(4))) float;
using u32x4  = __attribute__((ext_vector_type(4))) u32;

#define GLP(p) ((const __attribute__((address_space(1))) void*)(p))
#define LDSP(p) ((__attribute__((address_space(3))) void*)(p))

__device__ __forceinline__ float bf2f(u16 u) {
    union { float f; u32 i; } v; v.i = ((u32)u) << 16; return v.f;
}
__device__ __forceinline__ u16 f2bf(float f) {
    union { float f; u32 i; } v; v.f = f;
    u32 r = v.i + 0x7FFFu + ((v.i >> 16) & 1u);
    return (u16)(r >> 16);
}

// LLC-coherent primitives (bypass L1+L2; coherence point = LLC). Proven R4-R8.
__device__ __forceinline__ u32 ld_sc01_u32(const u32* p) {
    u32 v;
    asm volatile("global_load_dword %0, %1, off sc0 sc1\n\ts_waitcnt vmcnt(0)"
                 : "=v"(v) : "v"(p) : "memory");
    return v;
}
__device__ __forceinline__ void st_sc01_u32(u32* p, u32 v) {
    asm volatile("global_store_dword %0, %1, off sc0 sc1" :: "v"(p), "v"(v) : "memory");
}
__device__ __forceinline__ void st_sc01_u16(u16* p, u16 v) {
    asm volatile("global_store_short %0, %1, off sc0 sc1" :: "v"(p), "v"(v) : "memory");
}
__device__ __forceinline__ void st_sc01_u32x4(u16* p, u32x4 v) {
    asm volatile("global_store_dwordx4 %0, %1, off sc0 sc1" :: "v"(p), "v"(v) : "memory");
}

// ---------------- gather: X0[t*32+n][k] = bf16(emb[x[n][t]][k]) ----------------
__global__ void k_gather(const int* __restrict__ x, const float* __restrict__ emb,
                         u16* __restrict__ X0) {
    int gid = blockIdx.x * blockDim.x + threadIdx.x;
    if (gid >= 16384 * 256) return;
    int e4 = gid << 2;
    int m = e4 >> 10, k = e4 & 1023;
    int t = m >> 5, n = m & 31;
    int tok = x[n * 512 + t];
    float4 v = *reinterpret_cast<const float4*>(emb + ((size_t)tok << 10) + k);
    ushort4 o;
    o.x = f2bf(v.x); o.y = f2bf(v.y); o.z = f2bf(v.z); o.w = f2bf(v.w);
    *reinterpret_cast<ushort4*>(X0 + (size_t)e4) = o;
}

// ---------------- fp32 -> bf16 bulk convert ----------------
__global__ void k_f32bf16(const float* __restrict__ s, u16* __restrict__ d, int n4) {
    int gid = blockIdx.x * blockDim.x + threadIdx.x;
    if (gid >= n4) return;
    float4 v = reinterpret_cast<const float4*>(s)[gid];
    ushort4 o;
    o.x = f2bf(v.x); o.y = f2bf(v.y); o.z = f2bf(v.z); o.w = f2bf(v.w);
    reinterpret_cast<ushort4*>(d)[gid] = o;
}

// ---------------- GRU scan body R9 ------------------------------------------
// 8 WGs/dir x 768 threads, per-producer-wave gated staging:
//   wave w<8: spin flag[w] -> load producer-w's 64-col h slice -> stage to hS
//   waves 8-11: cached gdone gate -> stage gi (sc01, 3 chunks/thread)
// 3 barriers/step. Both layers symmetric (Gi produced in-kernel by chaser).
template<int LAYER>
__device__ __forceinline__ void gru_body(char* smem, int d, int wg,
    const u16* __restrict__ Gi, const u16* __restrict__ Whh_l,
    const float* __restrict__ bhh_l, u16* __restrict__ hbuf,
    u16* __restrict__ X1, float* __restrict__ hid, float* __restrict__ outp,
    u32* __restrict__ flags, u32* __restrict__ xflags, const u32* __restrict__ gdone)
{
    char* hS          = smem;                                // 32768 B (swizzled h)
    float (*ghs)[196] = (float(*)[196])(smem + 32768);       // 25088 B
    u16 (*gis)[208]   = (u16(*)[208])(smem + 57856);         // 13312 B
    float* bhh_s      = (float*)(smem + 71168);              //   768 B
    u16* hvS          = (u16*)(smem + 71936);                //  4096 B [32][64]
    const int tid = threadIdx.x;
    const int lane = tid & 63, w = tid >> 6;                 // w in [0,12)
    const int j0 = wg * 64;
    const int g = w >> 2;
    const int lr = lane & 15, lk = lane >> 4;

    if (tid < 192) {
        int g2 = tid >> 6, jj = tid & 63;
        bhh_s[tid] = bhh_l[d * 1536 + g2 * 512 + j0 + jj];
    }
    // pin W_hh fragments (16 k-tiles x 4 VGPRs = 64 VGPR/thread)
    bf16x8 wf[16];
    {
        const int joff = (w & 3) * 16;
        const u16* wr = Whh_l + (size_t)(d * 1536 + g * 512 + j0 + joff + lr) * 512 + lk * 8;
        #pragma unroll
        for (int kt = 0; kt < 16; ++kt)
            wf[kt] = *reinterpret_cast<const bf16x8*>(wr + kt * 32);
    }
    __syncthreads();

    u32* myflag = flags + (d * 8 + wg) * 32;
    const u32* wflag = flags + (d * 8 + (w & 7)) * 32;   // producer wave w polls
    u32* myxflag = (LAYER == 0) ? xflags + (d * 8 + wg) * 32 : nullptr;

    // h-staging geometry (waves 0-7): lane -> (col chunk, row base)
    const int c8 = (lane & 7) * 8;       // u16 col within 64-col slice
    const int rb = lane >> 3;            // row base 0..7
    const int colu = w * 64 + c8;        // absolute u16 col (wave w slice)
    // gi-staging base chunk (waves 8-11)
    const int ci0 = (tid - 512) * 3;

    float hp0 = 0.f, hp1 = 0.f, hp2 = 0.f;
    u32 g_seen = 0;

    for (int t = 0; t < 512; ++t) {
        // ==== A: gated parallel staging ====
        if (w < 8) {
            if (t > 0) {
                long long tt0 = __builtin_amdgcn_s_memrealtime();
                while (ld_sc01_u32(wflag) < (u32)t) {
                    __builtin_amdgcn_s_sleep(1);
                    if (__builtin_amdgcn_s_memrealtime() - tt0 > 2000) {  // 20 us
                        if (lane == 0)
                            __hip_atomic_store(myflag, (u32)t, __ATOMIC_RELEASE,
                                               __HIP_MEMORY_SCOPE_AGENT);
                        tt0 = __builtin_amdgcn_s_memrealtime();
                    }
                }
            }
            const u16* hb = hbuf + ((size_t)d * 2 + ((t + 1) & 1)) * 16384;
            u32x4 v0, v1, v2, v3;
            asm volatile("global_load_dwordx4 %0, %1, off sc0 sc1"
                         : "=v"(v0) : "v"(hb + (size_t)(rb)      * 512 + colu));
            asm volatile("global_load_dwordx4 %0, %1, off sc0 sc1"
                         : "=v"(v1) : "v"(hb + (size_t)(rb + 8)  * 512 + colu));
            asm volatile("global_load_dwordx4 %0, %1, off sc0 sc1"
                         : "=v"(v2) : "v"(hb + (size_t)(rb + 16) * 512 + colu));
            asm volatile("global_load_dwordx4 %0, %1, off sc0 sc1"
                         : "=v"(v3) : "v"(hb + (size_t)(rb + 24) * 512 + colu));
            asm volatile("s_waitcnt vmcnt(0)" ::: "memory");
            const int cb = colu * 2;
            *reinterpret_cast<u32x4*>(hS + (rb)      * 1024 + (cb ^ (((rb)      & 15) << 4))) = v0;
            *reinterpret_cast<u32x4*>(hS + (rb + 8)  * 1024 + (cb ^ (((rb + 8)  & 15) << 4))) = v1;
            *reinterpret_cast<u32x4*>(hS + (rb + 16) * 1024 + (cb ^ (((rb + 16) & 15) << 4))) = v2;
            *reinterpret_cast<u32x4*>(hS + (rb + 24) * 1024 + (cb ^ (((rb + 24) & 15) << 4))) = v3;
        } else {
            u32 yneed = (u32)(t >> 2);
            if (g_seen <= yneed) {
                const u32* gp = gdone + yneed;
                long long T0 = __builtin_amdgcn_s_memrealtime();
                while (ld_sc01_u32(gp) == 0) {
                    __builtin_amdgcn_s_sleep(1);
                    if (__builtin_amdgcn_s_memrealtime() - T0 > 2000000) break;  // 20 ms
                }
                g_seen = yneed + 1;
            }
            u32x4 gq[3];
            int nbs[3], gcs[3];
            #pragma unroll
            for (int i = 0; i < 3; ++i) {
                int ci = ci0 + i;
                nbs[i] = ci / 24; gcs[i] = ci % 24;
                const u16* gp = Gi + (size_t)(t * 32 + nbs[i]) * 3072 + d * 1536
                              + (gcs[i] >> 3) * 512 + j0 + (gcs[i] & 7) * 8;
                asm volatile("global_load_dwordx4 %0, %1, off sc0 sc1"
                             : "=v"(gq[i]) : "v"(gp));
            }
            asm volatile("s_waitcnt vmcnt(0)" ::: "memory");
            #pragma unroll
            for (int i = 0; i < 3; ++i)
                *reinterpret_cast<u32x4*>(&gis[nbs[i]][gcs[i] * 8]) = gq[i];
        }
        __syncthreads();   // B1: hS + gis staged

        // ==== B: MFMA + ghs ====
        f32x4 acc0 = {0.f, 0.f, 0.f, 0.f}, acc1 = acc0;
        #pragma unroll
        for (int kt = 0; kt < 16; ++kt) {
            int boff = (lk * 16 + kt * 64) ^ (lr << 4);
            bf16x8 a0 = *reinterpret_cast<const bf16x8*>(hS + lr * 1024 + boff);
            bf16x8 a1 = *reinterpret_cast<const bf16x8*>(hS + (16 + lr) * 1024 + boff);
            acc0 = __builtin_amdgcn_mfma_f32_16x16x32_bf16(a0, wf[kt], acc0, 0, 0, 0);
            acc1 = __builtin_amdgcn_mfma_f32_16x16x32_bf16(a1, wf[kt], acc1, 0, 0, 0);
        }
        int colg = w * 16 + lr;
        float bv = bhh_s[colg];
        #pragma unroll
        for (int q = 0; q < 4; ++q) {
            ghs[lk * 4 + q][colg]      = acc0[q] + bv;
            ghs[16 + lk * 4 + q][colg] = acc1[q] + bv;
        }
        __syncthreads();   // B2: ghs ready

        // ==== C: gates + h' ; h -> global sc01 + hvS ====
        u16* hbw = hbuf + ((size_t)d * 2 + (t & 1)) * 16384;
        #pragma unroll
        for (int rep = 0; rep < 3; ++rep) {
            int e = tid + rep * 768;
            if (e < 2048) {
                int j = e & 63, nb = e >> 6;
                float gr = bf2f(gis[nb][j])       + ghs[nb][j];
                float gz = bf2f(gis[nb][64 + j])  + ghs[nb][64 + j];
                float r = 1.f / (1.f + __expf(-gr));
                float z = 1.f / (1.f + __expf(-gz));
                float ng = tanhf(bf2f(gis[nb][128 + j]) + r * ghs[nb][128 + j]);
                float hp = (rep == 0) ? hp0 : (rep == 1) ? hp1 : hp2;
                float hv = (1.f - z) * ng + z * hp;
                if (rep == 0) hp0 = hv; else if (rep == 1) hp1 = hv; else hp2 = hv;
                u16 hb16 = f2bf(hv);
                st_sc01_u16(hbw + (size_t)nb * 512 + j0 + j, hb16);
                hvS[nb * 64 + j] = hb16;
            }
        }
        asm volatile("s_waitcnt vmcnt(0)" ::: "memory");   // h stores acked at LLC
        __syncthreads();   // B3
        if (tid == 16)
            st_sc01_u32(myflag, (u32)(t + 1));

        // ==== D: deferred outputs, tid>=512 (from hvS) ====
        if (tid >= 512) {
            int q = tid - 512, nb = q >> 3, j8 = (q & 7) * 8;
            union { u32x4 v; u16 s[8]; } h8;
            h8.v = *reinterpret_cast<const u32x4*>(hvS + nb * 64 + j8);
            float f0 = bf2f(h8.s[0]), f1 = bf2f(h8.s[1]), f2 = bf2f(h8.s[2]), f3 = bf2f(h8.s[3]);
            float f4 = bf2f(h8.s[4]), f5 = bf2f(h8.s[5]), f6 = bf2f(h8.s[6]), f7 = bf2f(h8.s[7]);
            float* hp = hid + ((size_t)(t * 4 + LAYER * 2 + d) * 32 + nb) * 512 + j0 + j8;
            *reinterpret_cast<float4*>(hp)     = make_float4(f0, f1, f2, f3);
            *reinterpret_cast<float4*>(hp + 4) = make_float4(f4, f5, f6, f7);
            if (LAYER == 0) {
                u16* xp = X1 + (size_t)(t * 32 + nb) * 1024 + (size_t)d * 512 + j0 + j8;
                st_sc01_u32x4(xp, h8.v);
            } else {
                float* op = outp + ((size_t)nb * 512 + t) * 1024 + (size_t)d * 512 + j0 + j8;
                *reinterpret_cast<float4*>(op)     = make_float4(f0, f1, f2, f3);
                *reinterpret_cast<float4*>(op + 4) = make_float4(f4, f5, f6, f7);
            }
        }
        // ==== E: X1 visibility flag at chaser granularity (every 4 steps) ====
        if (LAYER == 0 && (t & 3) == 3) {
            asm volatile("s_waitcnt vmcnt(0)" ::: "memory");  // X1 at LLC
            __syncthreads();
            if (tid == 17)
                st_sc01_u32(myxflag, (u32)(t + 1));
        }
    }
}

// ---------------- chaser GEMM (48 WGs per phase; waves 0-5 compute) ----------
// Tiles 128x96, K=1024; tile T = cw + 48k: y=T>>5, x=T&31 (deadline-ordered).
// xflags==nullptr -> ungated (gemm0). Epilogue sc01 -> Gi; cnt[y]==32 -> done[y].
__device__ __forceinline__ void chaser_body(char* smem, int cw,
    const u16* __restrict__ A, const u16* __restrict__ B,
    const float* __restrict__ bias, u16* __restrict__ Gi,
    const u32* __restrict__ xflags, u32* __restrict__ cnt, u32* __restrict__ done)
{
    u16* As = (u16*)smem;            // 16 KB
    u16* Bs = (u16*)(smem + 16384);  // 12 KB
    const int tid = threadIdx.x;
    const int lane = tid & 63, wid = tid >> 6;
    const int wm = wid & 1, wn = wid >> 1;
    const int lr = lane & 15, lk = lane >> 4;

    for (int T = cw; T < 4096; T += 48) {
        const int y = T >> 5, x = T & 31;
        if (xflags && tid < 16) {
            const u32* fp = xflags + tid * 32;
            u32 target = 4u * (u32)y + 4u;
            long long T0 = __builtin_amdgcn_s_memrealtime();
            while (ld_sc01_u32(fp) < target) {
                __builtin_amdgcn_s_sleep(4);
                if (__builtin_amdgcn_s_memrealtime() - T0 > 2000000) break;  // 20 ms
            }
        }
        __syncthreads();

        f32x4 zero = {0.f, 0.f, 0.f, 0.f};
        f32x4 acc[4][2];
        #pragma unroll
        for (int i = 0; i < 4; ++i) { acc[i][0] = zero; acc[i][1] = zero; }

        for (int k0 = 0; k0 < 1024; k0 += 64) {
            #pragma unroll
            for (int r = 0; r < 5; ++r) {
                int c = wid * 5 + r;               // wid>=6 -> c>=30 -> skipped
                if (c < 16) {
                    int o = c * 1024 + lane * 16;
                    int row = o >> 7, kb = o & 127;
                    int kbs = kb ^ ((row & 7) << 4);
                    const char* s = (const char*)A + ((size_t)(y * 128 + row) * 1024 + k0) * 2 + kbs;
                    __builtin_amdgcn_global_load_lds(GLP(s), LDSP((char*)As + c * 1024), 16, 0, 0);
                } else if (c < 28) {
                    int c2 = c - 16;
                    int o = c2 * 1024 + lane * 16;
                    int row = o >> 7, kb = o & 127;
                    int kbs = kb ^ ((row & 7) << 4);
                    const char* s = (const char*)B + ((size_t)(x * 96 + row) * 1024 + k0) * 2 + kbs;
                    __builtin_amdgcn_global_load_lds(GLP(s), LDSP((char*)Bs + c2 * 1024), 16, 0, 0);
                }
            }
            __syncthreads();
            if (wid < 6) {
                #pragma unroll
                for (int kk = 0; kk < 2; ++kk) {
                    bf16x8 af[4], bfr[2];
                    int kb = kk * 64 + lk * 16;
                    #pragma unroll
                    for (int i = 0; i < 4; ++i) {
                        int rowA = wm * 64 + i * 16 + lr;
                        af[i] = *reinterpret_cast<const bf16x8*>((const char*)As + rowA * 128 + (kb ^ ((rowA & 7) << 4)));
                    }
                    #pragma unroll
                    for (int j = 0; j < 2; ++j) {
                        int rowB = wn * 32 + j * 16 + lr;
                        bfr[j] = *reinterpret_cast<const bf16x8*>((const char*)Bs + rowB * 128 + (kb ^ ((rowB & 7) << 4)));
                    }
                    #pragma unroll
                    for (int i = 0; i < 4; ++i)
                        #pragma unroll
                        for (int j = 0; j < 2; ++j)
                            acc[i][j] = __builtin_amdgcn_mfma_f32_16x16x32_bf16(af[i], bfr[j], acc[i][j], 0, 0, 0);
                }
            }
            __syncthreads();
        }
        if (wid < 6) {
            #pragma unroll
            for (int j = 0; j < 2; ++j) {
                int col = x * 96 + wn * 32 + j * 16 + lr;
                float bv = bias[col];
                #pragma unroll
                for (int i = 0; i < 4; ++i) {
                    int rowb = y * 128 + wm * 64 + i * 16 + lk * 4;
                    #pragma unroll
                    for (int q = 0; q < 4; ++q)
                        st_sc01_u16(Gi + (size_t)(rowb + q) * 3072 + col, f2bf(acc[i][j][q] + bv));
                }
            }
        }
        asm volatile("s_waitcnt vmcnt(0)" ::: "memory");
        __syncthreads();
        if (tid == 0) {
            u32 old = __hip_atomic_fetch_add(&cnt[y], 1u, __ATOMIC_RELAXED,
                                             __HIP_MEMORY_SCOPE_AGENT);
            if (old == 31u)
                st_sc01_u32((u32*)&done[y], 1u);
        }
    }
}

// -------- fused: gru0(16) | gemm0-chaser(48) | gemm1-chaser(48) | gru1(16) ----
__global__ __launch_bounds__(768, 2) void k_fused(
    u16* __restrict__ Gi,
    const u16* __restrict__ X0, const u16* __restrict__ Wih,
    const float* __restrict__ b_ih,
    const u16* __restrict__ Whh, const float* __restrict__ bhh,
    u16* __restrict__ hbuf0, u16* __restrict__ hbuf1,
    u16* __restrict__ X1,
    float* __restrict__ hid, float* __restrict__ outp,
    u32* __restrict__ flags0, u32* __restrict__ flags1,
    u32* __restrict__ xflags,
    u32* __restrict__ g0cnt, u32* __restrict__ g0done,
    u32* __restrict__ g1cnt, u32* __restrict__ g1done)
{
    __shared__ __align__(16) char smem[76032];
    int bid = blockIdx.x;
    if (bid < 16) {
        gru_body<0>(smem, bid >> 3, bid & 7, Gi, Whh, bhh, hbuf0,
                    X1, hid, outp, flags0, xflags, g0done);
    } else if (bid < 64) {
        chaser_body(smem, bid - 16, X0, Wih, b_ih, Gi, nullptr, g0cnt, g0done);
    } else if (bid < 112) {
        chaser_body(smem, bid - 64, X1, Wih + (size_t)3072 * 1024, b_ih + 3072,
                    Gi, xflags, g1cnt, g1done);
    } else {
        int b = bid - 112;
        gru_body<1>(smem, b >> 3, b & 7, Gi, Whh + (size_t)3072 * 512, bhh + 3072,
                    hbuf1, nullptr, hid, outp, flags1, nullptr, g1done);
    }
}

extern "C" void kernel_launch(void* const* d_in, const int* in_sizes, int n_in,
                              void* d_out, int out_size, void* d_ws, size_t ws_size,
                              hipStream_t stream) {
    const int*   x    = (const int*)d_in[0];
    const float* emb  = (const float*)d_in[1];
    const float* w_ih = (const float*)d_in[2];
    const float* w_hh = (const float*)d_in[3];
    const float* b_ih = (const float*)d_in[4];
    const float* b_hh = (const float*)d_in[5];
    float* outp = (float*)d_out;
    float* hid  = outp + (size_t)32 * 512 * 1024;

    char* ws = (char*)d_ws;
    u16* X0     = (u16*)(ws);                  //  33,554,432 B
    u16* X1     = (u16*)(ws + 33554432);       //  33,554,432 B
    u16* Wih    = (u16*)(ws + 67108864);       //  12,582,912 B
    u16* Whh    = (u16*)(ws + 79691776);       //   6,291,456 B
    u16* Gi     = (u16*)(ws + 85983232);       // 100,663,296 B
    u16* hbuf0  = (u16*)(ws + 186646528);      //     131,072 B
    u16* hbuf1  = (u16*)(ws + 186777600);      //     131,072 B
    u32* flags0 = (u32*)(ws + 186908672);      //       2,048 B  [2][8][32]
    u32* flags1 = (u32*)(ws + 186910720);      //       2,048 B
    u32* xflags = (u32*)(ws + 186912768);      //       2,048 B  [2][8][32]
    u32* g0cnt  = (u32*)(ws + 186914816);      //         512 B
    u32* g0done = (u32*)(ws + 186915328);      //         512 B
    u32* g1cnt  = (u32*)(ws + 186915840);      //         512 B
    u32* g1done = (u32*)(ws + 186916352);      //         512 B

    k_gather<<<16384, 256, 0, stream>>>(x, emb, X0);
    k_f32bf16<<<(1572864 + 255) / 256, 256, 0, stream>>>(w_ih, Wih, 1572864);
    k_f32bf16<<<( 786432 + 255) / 256, 256, 0, stream>>>(w_hh, Whh, 786432);

    // zero hbuf0|hbuf1|flags0|flags1|xflags|g0cnt|g0done|g1cnt|g1done (contiguous)
    (void)hipMemsetAsync(hbuf0, 0, 270336, stream);

    // fused pipeline: gru0 | gemm0-chaser | gemm1-chaser | gru1
    k_fused<<<128, 768, 0, stream>>>(Gi, X0, Wih, b_ih, Whh, b_hh,
                                     hbuf0, hbuf1, X1, hid, outp,
                                     flags0, flags1, xflags,
                                     g0cnt, g0done, g1cnt, g1done);
}

// Round 10
// 2140.579 us; speedup vs baseline: 4.9973x; 1.0004x over previous
//
#include <hip/hip_runtime.h>
#include <hip/hip_bf16.h>

using u16 = unsigned short;
using u32 = unsigned int;
using bf16x8 = __attribute__((ext_vector_type(8))) __bf16;
using f32x4  = __attribute__((ext_vector_type(4))) float;
using u32x4  = __attribute__((ext_vector_type(4))) u32;

#define GLP(p) ((const __attribute__((address_space(1))) void*)(p))
#define LDSP(p) ((__attribute__((address_space(3))) void*)(p))

__device__ __forceinline__ float bf2f(u16 u) {
    union { float f; u32 i; } v; v.i = ((u32)u) << 16; return v.f;
}
__device__ __forceinline__ u16 f2bf(float f) {
    union { float f; u32 i; } v; v.f = f;
    u32 r = v.i + 0x7FFFu + ((v.i >> 16) & 1u);
    return (u16)(r >> 16);
}

// LLC-coherent primitives (bypass L1+L2; coherence point = LLC). Proven R4-R8.
__device__ __forceinline__ u32 ld_sc01_u32(const u32* p) {
    u32 v;
    asm volatile("global_load_dword %0, %1, off sc0 sc1\n\ts_waitcnt vmcnt(0)"
                 : "=v"(v) : "v"(p) : "memory");
    return v;
}
__device__ __forceinline__ void st_sc01_u32(u32* p, u32 v) {
    asm volatile("global_store_dword %0, %1, off sc0 sc1" :: "v"(p), "v"(v) : "memory");
}
__device__ __forceinline__ void st_sc01_u16(u16* p, u16 v) {
    asm volatile("global_store_short %0, %1, off sc0 sc1" :: "v"(p), "v"(v) : "memory");
}
__device__ __forceinline__ void st_sc01_u32x4(u16* p, u32x4 v) {
    asm volatile("global_store_dwordx4 %0, %1, off sc0 sc1" :: "v"(p), "v"(v) : "memory");
}

// ---------------- gather: X0[t*32+n][k] = bf16(emb[x[n][t]][k]) ----------------
__global__ void k_gather(const int* __restrict__ x, const float* __restrict__ emb,
                         u16* __restrict__ X0) {
    int gid = blockIdx.x * blockDim.x + threadIdx.x;
    if (gid >= 16384 * 256) return;
    int e4 = gid << 2;
    int m = e4 >> 10, k = e4 & 1023;
    int t = m >> 5, n = m & 31;
    int tok = x[n * 512 + t];
    float4 v = *reinterpret_cast<const float4*>(emb + ((size_t)tok << 10) + k);
    ushort4 o;
    o.x = f2bf(v.x); o.y = f2bf(v.y); o.z = f2bf(v.z); o.w = f2bf(v.w);
    *reinterpret_cast<ushort4*>(X0 + (size_t)e4) = o;
}

// ---------------- fp32 -> bf16 bulk convert ----------------
__global__ void k_f32bf16(const float* __restrict__ s, u16* __restrict__ d, int n4) {
    int gid = blockIdx.x * blockDim.x + threadIdx.x;
    if (gid >= n4) return;
    float4 v = reinterpret_cast<const float4*>(s)[gid];
    ushort4 o;
    o.x = f2bf(v.x); o.y = f2bf(v.y); o.z = f2bf(v.z); o.w = f2bf(v.w);
    reinterpret_cast<ushort4*>(d)[gid] = o;
}

// ---------------- GRU scan body R9 ------------------------------------------
// 8 WGs/dir x 768 threads, per-producer-wave gated staging:
//   wave w<8: spin flag[w] -> load producer-w's 64-col h slice -> stage to hS
//   waves 8-11: cached gdone gate -> stage gi (sc01, 3 chunks/thread)
// 3 barriers/step. Both layers symmetric (Gi produced in-kernel by chaser).
template<int LAYER>
__device__ __forceinline__ void gru_body(char* smem, int d, int wg,
    const u16* __restrict__ Gi, const u16* __restrict__ Whh_l,
    const float* __restrict__ bhh_l, u16* __restrict__ hbuf,
    u16* __restrict__ X1, float* __restrict__ hid, float* __restrict__ outp,
    u32* __restrict__ flags, u32* __restrict__ xflags, const u32* __restrict__ gdone)
{
    char* hS          = smem;                                // 32768 B (swizzled h)
    float (*ghs)[196] = (float(*)[196])(smem + 32768);       // 25088 B
    u16 (*gis)[208]   = (u16(*)[208])(smem + 57856);         // 13312 B
    float* bhh_s      = (float*)(smem + 71168);              //   768 B
    u16* hvS          = (u16*)(smem + 71936);                //  4096 B [32][64]
    const int tid = threadIdx.x;
    const int lane = tid & 63, w = tid >> 6;                 // w in [0,12)
    const int j0 = wg * 64;
    const int g = w >> 2;
    const int lr = lane & 15, lk = lane >> 4;

    if (tid < 192) {
        int g2 = tid >> 6, jj = tid & 63;
        bhh_s[tid] = bhh_l[d * 1536 + g2 * 512 + j0 + jj];
    }
    // pin W_hh fragments (16 k-tiles x 4 VGPRs = 64 VGPR/thread)
    bf16x8 wf[16];
    {
        const int joff = (w & 3) * 16;
        const u16* wr = Whh_l + (size_t)(d * 1536 + g * 512 + j0 + joff + lr) * 512 + lk * 8;
        #pragma unroll
        for (int kt = 0; kt < 16; ++kt)
            wf[kt] = *reinterpret_cast<const bf16x8*>(wr + kt * 32);
    }
    __syncthreads();

    u32* myflag = flags + (d * 8 + wg) * 32;
    const u32* wflag = flags + (d * 8 + (w & 7)) * 32;   // producer wave w polls
    u32* myxflag = (LAYER == 0) ? xflags + (d * 8 + wg) * 32 : nullptr;

    // h-staging geometry (waves 0-7): lane -> (col chunk, row base)
    const int c8 = (lane & 7) * 8;       // u16 col within 64-col slice
    const int rb = lane >> 3;            // row base 0..7
    const int colu = w * 64 + c8;        // absolute u16 col (wave w slice)
    // gi-staging base chunk (waves 8-11)
    const int ci0 = (tid - 512) * 3;

    float hp0 = 0.f, hp1 = 0.f, hp2 = 0.f;
    u32 g_seen = 0;

    for (int t = 0; t < 512; ++t) {
        // ==== A: gated parallel staging ====
        if (w < 8) {
            if (t > 0) {
                long long tt0 = __builtin_amdgcn_s_memrealtime();
                while (ld_sc01_u32(wflag) < (u32)t) {
                    __builtin_amdgcn_s_sleep(1);
                    if (__builtin_amdgcn_s_memrealtime() - tt0 > 2000) {  // 20 us
                        if (lane == 0)
                            __hip_atomic_store(myflag, (u32)t, __ATOMIC_RELEASE,
                                               __HIP_MEMORY_SCOPE_AGENT);
                        tt0 = __builtin_amdgcn_s_memrealtime();
                    }
                }
            }
            const u16* hb = hbuf + ((size_t)d * 2 + ((t + 1) & 1)) * 16384;
            u32x4 v0, v1, v2, v3;
            asm volatile("global_load_dwordx4 %0, %1, off sc0 sc1"
                         : "=v"(v0) : "v"(hb + (size_t)(rb)      * 512 + colu));
            asm volatile("global_load_dwordx4 %0, %1, off sc0 sc1"
                         : "=v"(v1) : "v"(hb + (size_t)(rb + 8)  * 512 + colu));
            asm volatile("global_load_dwordx4 %0, %1, off sc0 sc1"
                         : "=v"(v2) : "v"(hb + (size_t)(rb + 16) * 512 + colu));
            asm volatile("global_load_dwordx4 %0, %1, off sc0 sc1"
                         : "=v"(v3) : "v"(hb + (size_t)(rb + 24) * 512 + colu));
            asm volatile("s_waitcnt vmcnt(0)" ::: "memory");
            const int cb = colu * 2;
            *reinterpret_cast<u32x4*>(hS + (rb)      * 1024 + (cb ^ (((rb)      & 15) << 4))) = v0;
            *reinterpret_cast<u32x4*>(hS + (rb + 8)  * 1024 + (cb ^ (((rb + 8)  & 15) << 4))) = v1;
            *reinterpret_cast<u32x4*>(hS + (rb + 16) * 1024 + (cb ^ (((rb + 16) & 15) << 4))) = v2;
            *reinterpret_cast<u32x4*>(hS + (rb + 24) * 1024 + (cb ^ (((rb + 24) & 15) << 4))) = v3;
        } else {
            u32 yneed = (u32)(t >> 2);
            if (g_seen <= yneed) {
                const u32* gp = gdone + yneed;
                long long T0 = __builtin_amdgcn_s_memrealtime();
                while (ld_sc01_u32(gp) == 0) {
                    __builtin_amdgcn_s_sleep(1);
                    if (__builtin_amdgcn_s_memrealtime() - T0 > 2000000) break;  // 20 ms
                }
                g_seen = yneed + 1;
            }
            u32x4 gq[3];
            int nbs[3], gcs[3];
            #pragma unroll
            for (int i = 0; i < 3; ++i) {
                int ci = ci0 + i;
                nbs[i] = ci / 24; gcs[i] = ci % 24;
                const u16* gp = Gi + (size_t)(t * 32 + nbs[i]) * 3072 + d * 1536
                              + (gcs[i] >> 3) * 512 + j0 + (gcs[i] & 7) * 8;
                asm volatile("global_load_dwordx4 %0, %1, off sc0 sc1"
                             : "=v"(gq[i]) : "v"(gp));
            }
            asm volatile("s_waitcnt vmcnt(0)" ::: "memory");
            #pragma unroll
            for (int i = 0; i < 3; ++i)
                *reinterpret_cast<u32x4*>(&gis[nbs[i]][gcs[i] * 8]) = gq[i];
        }
        __syncthreads();   // B1: hS + gis staged

        // ==== B: MFMA + ghs ====
        f32x4 acc0 = {0.f, 0.f, 0.f, 0.f}, acc1 = acc0;
        #pragma unroll
        for (int kt = 0; kt < 16; ++kt) {
            int boff = (lk * 16 + kt * 64) ^ (lr << 4);
            bf16x8 a0 = *reinterpret_cast<const bf16x8*>(hS + lr * 1024 + boff);
            bf16x8 a1 = *reinterpret_cast<const bf16x8*>(hS + (16 + lr) * 1024 + boff);
            acc0 = __builtin_amdgcn_mfma_f32_16x16x32_bf16(a0, wf[kt], acc0, 0, 0, 0);
            acc1 = __builtin_amdgcn_mfma_f32_16x16x32_bf16(a1, wf[kt], acc1, 0, 0, 0);
        }
        int colg = w * 16 + lr;
        float bv = bhh_s[colg];
        #pragma unroll
        for (int q = 0; q < 4; ++q) {
            ghs[lk * 4 + q][colg]      = acc0[q] + bv;
            ghs[16 + lk * 4 + q][colg] = acc1[q] + bv;
        }
        __syncthreads();   // B2: ghs ready

        // ==== C: gates + h' ; h -> global sc01 + hvS ====
        u16* hbw = hbuf + ((size_t)d * 2 + (t & 1)) * 16384;
        #pragma unroll
        for (int rep = 0; rep < 3; ++rep) {
            int e = tid + rep * 768;
            if (e < 2048) {
                int j = e & 63, nb = e >> 6;
                float gr = bf2f(gis[nb][j])       + ghs[nb][j];
                float gz = bf2f(gis[nb][64 + j])  + ghs[nb][64 + j];
                float r = 1.f / (1.f + __expf(-gr));
                float z = 1.f / (1.f + __expf(-gz));
                float ng = tanhf(bf2f(gis[nb][128 + j]) + r * ghs[nb][128 + j]);
                float hp = (rep == 0) ? hp0 : (rep == 1) ? hp1 : hp2;
                float hv = (1.f - z) * ng + z * hp;
                if (rep == 0) hp0 = hv; else if (rep == 1) hp1 = hv; else hp2 = hv;
                u16 hb16 = f2bf(hv);
                st_sc01_u16(hbw + (size_t)nb * 512 + j0 + j, hb16);
                hvS[nb * 64 + j] = hb16;
            }
        }
        asm volatile("s_waitcnt vmcnt(0)" ::: "memory");   // h stores acked at LLC
        __syncthreads();   // B3
        if (tid == 16)
            st_sc01_u32(myflag, (u32)(t + 1));

        // ==== D: deferred outputs, tid>=512 (from hvS) ====
        if (tid >= 512) {
            int q = tid - 512, nb = q >> 3, j8 = (q & 7) * 8;
            union { u32x4 v; u16 s[8]; } h8;
            h8.v = *reinterpret_cast<const u32x4*>(hvS + nb * 64 + j8);
            float f0 = bf2f(h8.s[0]), f1 = bf2f(h8.s[1]), f2 = bf2f(h8.s[2]), f3 = bf2f(h8.s[3]);
            float f4 = bf2f(h8.s[4]), f5 = bf2f(h8.s[5]), f6 = bf2f(h8.s[6]), f7 = bf2f(h8.s[7]);
            float* hp = hid + ((size_t)(t * 4 + LAYER * 2 + d) * 32 + nb) * 512 + j0 + j8;
            *reinterpret_cast<float4*>(hp)     = make_float4(f0, f1, f2, f3);
            *reinterpret_cast<float4*>(hp + 4) = make_float4(f4, f5, f6, f7);
            if (LAYER == 0) {
                u16* xp = X1 + (size_t)(t * 32 + nb) * 1024 + (size_t)d * 512 + j0 + j8;
                st_sc01_u32x4(xp, h8.v);
            } else {
                float* op = outp + ((size_t)nb * 512 + t) * 1024 + (size_t)d * 512 + j0 + j8;
                *reinterpret_cast<float4*>(op)     = make_float4(f0, f1, f2, f3);
                *reinterpret_cast<float4*>(op + 4) = make_float4(f4, f5, f6, f7);
            }
        }
        // ==== E: X1 visibility flag at chaser granularity (every 4 steps) ====
        if (LAYER == 0 && (t & 3) == 3) {
            asm volatile("s_waitcnt vmcnt(0)" ::: "memory");  // X1 at LLC
            __syncthreads();
            if (tid == 17)
                st_sc01_u32(myxflag, (u32)(t + 1));
        }
    }
}

// ---------------- chaser GEMM (48 WGs per phase; waves 0-5 compute) ----------
// Tiles 128x96, K=1024; tile T = cw + 48k: y=T>>5, x=T&31 (deadline-ordered).
// xflags==nullptr -> ungated (gemm0). Epilogue sc01 -> Gi; cnt[y]==32 -> done[y].
__device__ __forceinline__ void chaser_body(char* smem, int cw,
    const u16* __restrict__ A, const u16* __restrict__ B,
    const float* __restrict__ bias, u16* __restrict__ Gi,
    const u32* __restrict__ xflags, u32* __restrict__ cnt, u32* __restrict__ done)
{
    u16* As = (u16*)smem;            // 16 KB
    u16* Bs = (u16*)(smem + 16384);  // 12 KB
    const int tid = threadIdx.x;
    const int lane = tid & 63, wid = tid >> 6;
    const int wm = wid & 1, wn = wid >> 1;
    const int lr = lane & 15, lk = lane >> 4;

    for (int T = cw; T < 4096; T += 48) {
        const int y = T >> 5, x = T & 31;
        if (xflags && tid < 16) {
            const u32* fp = xflags + tid * 32;
            u32 target = 4u * (u32)y + 4u;
            long long T0 = __builtin_amdgcn_s_memrealtime();
            while (ld_sc01_u32(fp) < target) {
                __builtin_amdgcn_s_sleep(4);
                if (__builtin_amdgcn_s_memrealtime() - T0 > 2000000) break;  // 20 ms
            }
        }
        __syncthreads();

        f32x4 zero = {0.f, 0.f, 0.f, 0.f};
        f32x4 acc[4][2];
        #pragma unroll
        for (int i = 0; i < 4; ++i) { acc[i][0] = zero; acc[i][1] = zero; }

        for (int k0 = 0; k0 < 1024; k0 += 64) {
            #pragma unroll
            for (int r = 0; r < 5; ++r) {
                int c = wid * 5 + r;               // wid>=6 -> c>=30 -> skipped
                if (c < 16) {
                    int o = c * 1024 + lane * 16;
                    int row = o >> 7, kb = o & 127;
                    int kbs = kb ^ ((row & 7) << 4);
                    const char* s = (const char*)A + ((size_t)(y * 128 + row) * 1024 + k0) * 2 + kbs;
                    __builtin_amdgcn_global_load_lds(GLP(s), LDSP((char*)As + c * 1024), 16, 0, 0);
                } else if (c < 28) {
                    int c2 = c - 16;
                    int o = c2 * 1024 + lane * 16;
                    int row = o >> 7, kb = o & 127;
                    int kbs = kb ^ ((row & 7) << 4);
                    const char* s = (const char*)B + ((size_t)(x * 96 + row) * 1024 + k0) * 2 + kbs;
                    __builtin_amdgcn_global_load_lds(GLP(s), LDSP((char*)Bs + c2 * 1024), 16, 0, 0);
                }
            }
            __syncthreads();
            if (wid < 6) {
                #pragma unroll
                for (int kk = 0; kk < 2; ++kk) {
                    bf16x8 af[4], bfr[2];
                    int kb = kk * 64 + lk * 16;
                    #pragma unroll
                    for (int i = 0; i < 4; ++i) {
                        int rowA = wm * 64 + i * 16 + lr;
                        af[i] = *reinterpret_cast<const bf16x8*>((const char*)As + rowA * 128 + (kb ^ ((rowA & 7) << 4)));
                    }
                    #pragma unroll
                    for (int j = 0; j < 2; ++j) {
                        int rowB = wn * 32 + j * 16 + lr;
                        bfr[j] = *reinterpret_cast<const bf16x8*>((const char*)Bs + rowB * 128 + (kb ^ ((rowB & 7) << 4)));
                    }
                    #pragma unroll
                    for (int i = 0; i < 4; ++i)
                        #pragma unroll
                        for (int j = 0; j < 2; ++j)
                            acc[i][j] = __builtin_amdgcn_mfma_f32_16x16x32_bf16(af[i], bfr[j], acc[i][j], 0, 0, 0);
                }
            }
            __syncthreads();
        }
        if (wid < 6) {
            #pragma unroll
            for (int j = 0; j < 2; ++j) {
                int col = x * 96 + wn * 32 + j * 16 + lr;
                float bv = bias[col];
                #pragma unroll
                for (int i = 0; i < 4; ++i) {
                    int rowb = y * 128 + wm * 64 + i * 16 + lk * 4;
                    #pragma unroll
                    for (int q = 0; q < 4; ++q)
                        st_sc01_u16(Gi + (size_t)(rowb + q) * 3072 + col, f2bf(acc[i][j][q] + bv));
                }
            }
        }
        asm volatile("s_waitcnt vmcnt(0)" ::: "memory");
        __syncthreads();
        if (tid == 0) {
            u32 old = __hip_atomic_fetch_add(&cnt[y], 1u, __ATOMIC_RELAXED,
                                             __HIP_MEMORY_SCOPE_AGENT);
            if (old == 31u)
                st_sc01_u32((u32*)&done[y], 1u);
        }
    }
}

// -------- fused: gru0(16) | gemm0-chaser(48) | gemm1-chaser(48) | gru1(16) ----
__global__ __launch_bounds__(768, 2) void k_fused(
    u16* __restrict__ Gi,
    const u16* __restrict__ X0, const u16* __restrict__ Wih,
    const float* __restrict__ b_ih,
    const u16* __restrict__ Whh, const float* __restrict__ bhh,
    u16* __restrict__ hbuf0, u16* __restrict__ hbuf1,
    u16* __restrict__ X1,
    float* __restrict__ hid, float* __restrict__ outp,
    u32* __restrict__ flags0, u32* __restrict__ flags1,
    u32* __restrict__ xflags,
    u32* __restrict__ g0cnt, u32* __restrict__ g0done,
    u32* __restrict__ g1cnt, u32* __restrict__ g1done)
{
    __shared__ __align__(16) char smem[76032];
    int bid = blockIdx.x;
    if (bid < 16) {
        gru_body<0>(smem, bid >> 3, bid & 7, Gi, Whh, bhh, hbuf0,
                    X1, hid, outp, flags0, xflags, g0done);
    } else if (bid < 64) {
        chaser_body(smem, bid - 16, X0, Wih, b_ih, Gi, nullptr, g0cnt, g0done);
    } else if (bid < 112) {
        chaser_body(smem, bid - 64, X1, Wih + (size_t)3072 * 1024, b_ih + 3072,
                    Gi, xflags, g1cnt, g1done);
    } else {
        int b = bid - 112;
        gru_body<1>(smem, b >> 3, b & 7, Gi, Whh + (size_t)3072 * 512, bhh + 3072,
                    hbuf1, nullptr, hid, outp, flags1, nullptr, g1done);
    }
}

extern "C" void kernel_launch(void* const* d_in, const int* in_sizes, int n_in,
                              void* d_out, int out_size, void* d_ws, size_t ws_size,
                              hipStream_t stream) {
    const int*   x    = (const int*)d_in[0];
    const float* emb  = (const float*)d_in[1];
    const float* w_ih = (const float*)d_in[2];
    const float* w_hh = (const float*)d_in[3];
    const float* b_ih = (const float*)d_in[4];
    const float* b_hh = (const float*)d_in[5];
    float* outp = (float*)d_out;
    float* hid  = outp + (size_t)32 * 512 * 1024;

    char* ws = (char*)d_ws;
    u16* X0     = (u16*)(ws);                  //  33,554,432 B
    u16* X1     = (u16*)(ws + 33554432);       //  33,554,432 B
    u16* Wih    = (u16*)(ws + 67108864);       //  12,582,912 B
    u16* Whh    = (u16*)(ws + 79691776);       //   6,291,456 B
    u16* Gi     = (u16*)(ws + 85983232);       // 100,663,296 B
    u16* hbuf0  = (u16*)(ws + 186646528);      //     131,072 B
    u16* hbuf1  = (u16*)(ws + 186777600);      //     131,072 B
    u32* flags0 = (u32*)(ws + 186908672);      //       2,048 B  [2][8][32]
    u32* flags1 = (u32*)(ws + 186910720);      //       2,048 B
    u32* xflags = (u32*)(ws + 186912768);      //       2,048 B  [2][8][32]
    u32* g0cnt  = (u32*)(ws + 186914816);      //         512 B
    u32* g0done = (u32*)(ws + 186915328);      //         512 B
    u32* g1cnt  = (u32*)(ws + 186915840);      //         512 B
    u32* g1done = (u32*)(ws + 186916352);      //         512 B

    k_gather<<<16384, 256, 0, stream>>>(x, emb, X0);
    k_f32bf16<<<(1572864 + 255) / 256, 256, 0, stream>>>(w_ih, Wih, 1572864);
    k_f32bf16<<<( 786432 + 255) / 256, 256, 0, stream>>>(w_hh, Whh, 786432);

    // zero hbuf0|hbuf1|flags0|flags1|xflags|g0cnt|g0done|g1cnt|g1done (contiguous)
    (void)hipMemsetAsync(hbuf0, 0, 270336, stream);

    // fused pipeline: gru0 | gemm0-chaser | gemm1-chaser | gru1
    k_fused<<<128, 768, 0, stream>>>(Gi, X0, Wih, b_ih, Whh, b_hh,
                                     hbuf0, hbuf1, X1, hid, outp,
                                     flags0, flags1, xflags,
                                     g0cnt, g0done, g1cnt, g1done);
}